// Round 8
// baseline (489.801 us; speedup 1.0000x reference)
//
#include <hip/hip_runtime.h>
#include <hip/hip_fp8.h>
#include <math.h>

#define N_NODES 100000
#define N_EDGES 1250000
#define IN_DIM 12
#define HID 64
#define N_LAYERS 3
#define LN_EPS 1e-5f
#define SLOPE 0.01f

#define NODE_BLOCKS ((N_NODES + 3) / 4)     // 4 waves (nodes) per 256-thread block
#define EDGE_TBLOCKS ((N_EDGES + 255) / 256)
#define SCAN_BLOCKS ((N_NODES + 1023) / 1024)   // 98
#define MFMA_BLOCKS ((N_NODES + 63) / 64)       // 64 nodes per 256-thread block
#define NEDGE_BLOCKS ((N_NODES + 255) / 256)    // node-parallel edge pass

#define BUCKETS 256
#define BUCKET_NODES 391                         // 256*391 = 100096 >= N_NODES
#define P1_EDGES 4096
#define P1_BLOCKS ((N_EDGES + P1_EDGES - 1) / P1_EDGES)  // 306

#define LEW_SCALE 2048.0f
#define LEW_INV (1.0f / 2048.0f)

typedef short bf16x8 __attribute__((ext_vector_type(8)));
typedef float f32x4 __attribute__((ext_vector_type(4)));

static __device__ __forceinline__ unsigned short f2bf(float f) {
  union { float f; unsigned int u; } v; v.f = f;
  unsigned int r = v.u + 0x7FFFu + ((v.u >> 16) & 1u);   // RNE
  return (unsigned short)(r >> 16);
}
static __device__ __forceinline__ unsigned char f2e4(float f) {
  return __hip_fp8_e4m3(f).__x;
}
static __device__ __forceinline__ float e42f(unsigned char b) {
  __hip_fp8_e4m3 d; d.__x = b;
  return (float)d;
}

// ---------------- input projection: h = x @ in_W + in_b ----------------
__global__ void k_in_proj(const float* __restrict__ x,
                          const float* __restrict__ W,   // [12][64]
                          const float* __restrict__ b,
                          float* __restrict__ h) {
  __shared__ float sW[IN_DIM * HID];
  for (int i = threadIdx.x; i < IN_DIM * HID; i += blockDim.x) sW[i] = W[i];
  __syncthreads();
  int wave = threadIdx.x >> 6, lane = threadIdx.x & 63;
  int n = blockIdx.x * 4 + wave;
  if (n >= N_NODES) return;
  float acc = b[lane];
#pragma unroll
  for (int k = 0; k < IN_DIM; ++k)
    acc += x[n * IN_DIM + k] * sW[k * HID + lane];
  h[n * HID + lane] = acc;
}

// ---------------- CSR build (once per launch) ----------------
__global__ void k_hist(const int* __restrict__ ei, int* __restrict__ deg) {
  int e = blockIdx.x * 256 + threadIdx.x;
  if (e >= N_EDGES) return;
  atomicAdd(&deg[ei[e]], 1);
}

__global__ void k_blocksums(const int* __restrict__ deg, int* __restrict__ bsum) {
  __shared__ int sm[1024];
  int i = blockIdx.x * 1024 + threadIdx.x;
  sm[threadIdx.x] = (i < N_NODES) ? deg[i] : 0;
  __syncthreads();
  for (int st = 512; st > 0; st >>= 1) {
    if (threadIdx.x < st) sm[threadIdx.x] += sm[threadIdx.x + st];
    __syncthreads();
  }
  if (threadIdx.x == 0) bsum[blockIdx.x] = sm[0];
}

__global__ void k_scan_bsums(int* __restrict__ bsum, int nb) {  // single block, 128 thr
  __shared__ int sm[128];
  int v = (threadIdx.x < nb) ? bsum[threadIdx.x] : 0;
  sm[threadIdx.x] = v;
  __syncthreads();
  for (int st = 1; st < 128; st <<= 1) {
    int t = (threadIdx.x >= st) ? sm[threadIdx.x - st] : 0;
    __syncthreads();
    sm[threadIdx.x] += t;
    __syncthreads();
  }
  if (threadIdx.x < nb) bsum[threadIdx.x] = sm[threadIdx.x] - v;  // exclusive
}

__global__ void k_scan_final(const int* __restrict__ deg, const int* __restrict__ bsum,
                             int* __restrict__ rowptr) {
  __shared__ int sm[1024];
  int i = blockIdx.x * 1024 + threadIdx.x;
  int v = (i < N_NODES) ? deg[i] : 0;
  sm[threadIdx.x] = v;
  __syncthreads();
  for (int st = 1; st < 1024; st <<= 1) {
    int t = (threadIdx.x >= st) ? sm[threadIdx.x - st] : 0;
    __syncthreads();
    sm[threadIdx.x] += t;
    __syncthreads();
  }
  int excl = sm[threadIdx.x] - v + bsum[blockIdx.x];
  if (i < N_NODES) rowptr[i] = excl;
}

// bucket write-cursors from rowptr (bucket b covers nodes [b*391, ...))
__global__ void k_bcur(const int* __restrict__ rowptr, unsigned* __restrict__ gbcur) {
  int b = threadIdx.x;
  if (b < BUCKETS) gbcur[b] = (unsigned)rowptr[b * BUCKET_NODES];
}

// pass 1: LDS-binned burst scatter of 8B records (row|col|qlew) into bucket regions
__global__ void k_fill_p1(const int* __restrict__ ei, const float* __restrict__ ew,
                          unsigned* __restrict__ gbcur,
                          unsigned long long* __restrict__ tmp) {
  __shared__ unsigned cnt[BUCKETS], gbase[BUCKETS], lofs[BUCKETS];
  int t = threadIdx.x;
  cnt[t] = 0;
  __syncthreads();
  int base = blockIdx.x * P1_EDGES;
#pragma unroll
  for (int i = 0; i < 16; ++i) {
    int e = base + i * 256 + t;
    if (e < N_EDGES) atomicAdd(&cnt[(unsigned)ei[e] / BUCKET_NODES], 1u);
  }
  __syncthreads();
  {
    unsigned c = cnt[t];
    gbase[t] = c ? atomicAdd(&gbcur[t], c) : 0u;
    lofs[t] = 0;
  }
  __syncthreads();
#pragma unroll
  for (int i = 0; i < 16; ++i) {
    int e = base + i * 256 + t;
    if (e < N_EDGES) {
      unsigned r = (unsigned)ei[e], c = (unsigned)ei[N_EDGES + e];
      float lew = __logf(ew[e]);
      lew = fmaxf(lew, -15.9995f);
      unsigned q = (unsigned)(-lew * LEW_SCALE + 0.5f);
      if (q > 32767u) q = 32767u;
      unsigned b = r / BUCKET_NODES;
      unsigned idx = atomicAdd(&lofs[b], 1u);
      tmp[gbase[b] + idx] = ((unsigned long long)r << 32)
                          | ((unsigned long long)c << 15) | q;
    }
  }
}

// pass 2: per-bucket exact placement; scattered 4B writes stay in one ~20KB L2 window
__global__ void k_fill_p2(const int* __restrict__ rowptr,
                          const unsigned long long* __restrict__ tmp,
                          unsigned* __restrict__ packed) {
  __shared__ int lcur[BUCKET_NODES];
  int b = blockIdx.x, t = threadIdx.x;
  int nb0 = b * BUCKET_NODES;
  int nb1 = min(nb0 + BUCKET_NODES, N_NODES);
  int nn = nb1 - nb0;
  for (int j = t; j < nn; j += 256) lcur[j] = rowptr[nb0 + j];
  __syncthreads();
  int beg = rowptr[nb0];
  int end = (nb1 < N_NODES) ? rowptr[nb1] : N_EDGES;
  for (int i = beg + t; i < end; i += 256) {
    unsigned long long rec = tmp[i];
    int r = (int)(rec >> 32);
    int pos = atomicAdd(&lcur[r - nb0], 1);
    packed[pos] = (unsigned)(rec & 0xFFFFFFFFu);
  }
}

// ---------------- per-layer u = W @ a  (alpha decomposition) ----------------
__global__ void k_prep(const float* __restrict__ lin_W,  // [3][64][64]
                       const float* __restrict__ lin_b,  // [3][64]
                       const float* __restrict__ att_W,  // [3][128]
                       float* __restrict__ uvec,         // [3][2][64]
                       float* __restrict__ ucst) {       // [3][2]
  int l = blockIdx.x, j = threadIdx.x;
  const float* Wl = lin_W + l * HID * HID;
  const float* a1 = att_W + l * 2 * HID;
  const float* a2 = a1 + HID;
  float s1 = 0.f, s2 = 0.f;
  for (int c = 0; c < HID; ++c) {
    float w = Wl[j * HID + c];
    s1 += w * a1[c];
    s2 += w * a2[c];
  }
  uvec[l * 128 + j] = s1;
  uvec[l * 128 + 64 + j] = s2;
  float t1 = lin_b[l * HID + j] * a1[j];
  float t2 = lin_b[l * HID + j] * a2[j];
#pragma unroll
  for (int off = 32; off > 0; off >>= 1) {
    t1 += __shfl_xor(t1, off, 64);
    t2 += __shfl_xor(t2, off, 64);
  }
  if (j == 0) { ucst[l * 2] = t1; ucst[l * 2 + 1] = t2; }
}

// ---------------- MFMA linear: hl = h@W + b (fp32 + fp8 mirror); alphas ----------------
__global__ void k_lin_mfma(const float* __restrict__ h,
                           const float* __restrict__ W,     // [64][64] this layer
                           const float* __restrict__ bias,  // [64]
                           const float* __restrict__ uvec,  // [2][64] this layer
                           const float* __restrict__ ucst,  // [2]
                           float* __restrict__ hl,
                           unsigned char* __restrict__ hl8, // fp8 e4m3 mirror
                           float* __restrict__ alpha1,
                           float* __restrict__ alpha2) {
  __shared__ unsigned short Wt[HID * 72];  // Wt[n][k] bf16, row stride 72
  for (int idx = threadIdx.x; idx < HID * HID; idx += 256) {
    int k = idx >> 6, n = idx & 63;
    Wt[n * 72 + k] = f2bf(W[idx]);
  }
  __syncthreads();

  int wave = threadIdx.x >> 6, lane = threadIdx.x & 63;
  int g = lane >> 4, r = lane & 15;
  int nb = blockIdx.x * 64 + wave * 16;
  int row = nb + r;
  bool rowok = row < N_NODES;

  f32x4 f0 = {0,0,0,0}, f1 = {0,0,0,0}, f2v = {0,0,0,0}, f3 = {0,0,0,0};
  if (rowok) {
    const float* hrow = h + (size_t)row * HID;
    f0  = *(const f32x4*)(hrow + g * 8);
    f1  = *(const f32x4*)(hrow + g * 8 + 4);
    f2v = *(const f32x4*)(hrow + 32 + g * 8);
    f3  = *(const f32x4*)(hrow + 32 + g * 8 + 4);
  }
  bf16x8 a0, a1f;
#pragma unroll
  for (int i = 0; i < 4; ++i) {
    a0[i]      = (short)f2bf(f0[i]);
    a0[i + 4]  = (short)f2bf(f1[i]);
    a1f[i]     = (short)f2bf(f2v[i]);
    a1f[i + 4] = (short)f2bf(f3[i]);
  }

  f32x4 acc[4] = {{0,0,0,0},{0,0,0,0},{0,0,0,0},{0,0,0,0}};
#pragma unroll
  for (int nt = 0; nt < 4; ++nt) {
    bf16x8 b0 = *(const bf16x8*)&Wt[(nt * 16 + r) * 72 + g * 8];
    bf16x8 b1 = *(const bf16x8*)&Wt[(nt * 16 + r) * 72 + 32 + g * 8];
    acc[nt] = __builtin_amdgcn_mfma_f32_16x16x32_bf16(a0, b0, acc[nt], 0, 0, 0);
    acc[nt] = __builtin_amdgcn_mfma_f32_16x16x32_bf16(a1f, b1, acc[nt], 0, 0, 0);
  }

  // alphas from fp32 h fragments
  {
    const float* u1 = uvec;
    const float* u2 = uvec + HID;
    f32x4 ua = *(const f32x4*)(u1 + g * 8),      ub = *(const f32x4*)(u1 + g * 8 + 4);
    f32x4 uc = *(const f32x4*)(u1 + 32 + g * 8), ud = *(const f32x4*)(u1 + 32 + g * 8 + 4);
    float p1 = f0[0]*ua[0]+f0[1]*ua[1]+f0[2]*ua[2]+f0[3]*ua[3]
             + f1[0]*ub[0]+f1[1]*ub[1]+f1[2]*ub[2]+f1[3]*ub[3]
             + f2v[0]*uc[0]+f2v[1]*uc[1]+f2v[2]*uc[2]+f2v[3]*uc[3]
             + f3[0]*ud[0]+f3[1]*ud[1]+f3[2]*ud[2]+f3[3]*ud[3];
    ua = *(const f32x4*)(u2 + g * 8);      ub = *(const f32x4*)(u2 + g * 8 + 4);
    uc = *(const f32x4*)(u2 + 32 + g * 8); ud = *(const f32x4*)(u2 + 32 + g * 8 + 4);
    float p2 = f0[0]*ua[0]+f0[1]*ua[1]+f0[2]*ua[2]+f0[3]*ua[3]
             + f1[0]*ub[0]+f1[1]*ub[1]+f1[2]*ub[2]+f1[3]*ub[3]
             + f2v[0]*uc[0]+f2v[1]*uc[1]+f2v[2]*uc[2]+f2v[3]*uc[3]
             + f3[0]*ud[0]+f3[1]*ud[1]+f3[2]*ud[2]+f3[3]*ud[3];
    p1 += __shfl_xor(p1, 16, 64); p1 += __shfl_xor(p1, 32, 64);
    p2 += __shfl_xor(p2, 16, 64); p2 += __shfl_xor(p2, 32, 64);
    if (g == 0 && rowok) {
      alpha1[row] = p1 + ucst[0];
      alpha2[row] = p2 + ucst[1];
    }
  }

  // store hl (+bias) fp32 + fp8 mirror. D: col = nt*16 + r, node = nb + g*4 + reg
#pragma unroll
  for (int nt = 0; nt < 4; ++nt) {
    float bv = bias[nt * 16 + r];
#pragma unroll
    for (int reg = 0; reg < 4; ++reg) {
      int n2 = nb + g * 4 + reg;
      if (n2 < N_NODES) {
        float v = acc[nt][reg] + bv;
        hl[(size_t)n2 * HID + nt * 16 + r] = v;
        hl8[(size_t)n2 * HID + nt * 16 + r] = f2e4(v);
      }
    }
  }
}

// ---------------- per-layer edge pass (node-parallel) + fused ticket combine ----------------
// thread n walks its CSR segment: slw[p] = leaky(score) - qlew; online max/sum of leaky(score)
__global__ void k_edge(const int* __restrict__ rowptr,
                       const int* __restrict__ deg,
                       const unsigned* __restrict__ packed,
                       const float* __restrict__ alpha1,
                       const float* __restrict__ alpha2,
                       const float* __restrict__ attB,
                       float* __restrict__ slw,
                       float* __restrict__ pmax,
                       float* __restrict__ psum,
                       int* __restrict__ counter,
                       float* __restrict__ red) {
  int t = threadIdx.x;
  int n = blockIdx.x * 256 + t;
  float m = -INFINITY, sum = 0.f;
  if (n < N_NODES) {
    float a1 = alpha1[n] + attB[0];
    int beg = rowptr[n];
    int end = beg + deg[n];
    for (int p = beg; p < end; ++p) {
      unsigned u = packed[p];
      float sc = a1 + alpha2[u >> 15];
      sc = sc > 0.f ? sc : SLOPE * sc;
      slw[p] = sc - (float)(u & 0x7FFFu) * LEW_INV;
      if (sc > m) { sum *= __expf(m - sc); m = sc; }
      sum += __expf(sc - m);
    }
  }
  __shared__ float smax[256], ssum[256];
  __shared__ bool last;
  smax[t] = m; ssum[t] = sum;
  __syncthreads();
  for (int st = 128; st > 0; st >>= 1) {
    if (t < st) {
      float ma = smax[t], mb = smax[t + st];
      float sa = ssum[t], sb = ssum[t + st];
      float mm = fmaxf(ma, mb);
      float ss = 0.f;
      if (mm != -INFINITY)
        ss = (ma == -INFINITY ? 0.f : sa * __expf(ma - mm))
           + (mb == -INFINITY ? 0.f : sb * __expf(mb - mm));
      smax[t] = mm; ssum[t] = ss;
    }
    __syncthreads();
  }
  if (t == 0) {
    pmax[blockIdx.x] = smax[0];
    psum[blockIdx.x] = ssum[0];
    __threadfence();
    int old = atomicAdd(counter, 1);
    last = (old == (int)gridDim.x - 1);
  }
  __syncthreads();
  if (!last) return;
  __threadfence();
  volatile const float* vpm = pmax;
  volatile const float* vps = psum;
  float m2 = -INFINITY, s2 = 0.f;
  for (int i = t; i < (int)gridDim.x; i += 256) {
    float mb = vpm[i], sb = vps[i];
    if (mb != -INFINITY) {
      if (mb > m2) { s2 *= __expf(m2 - mb); m2 = mb; }
      s2 += sb * __expf(mb - m2);
    }
  }
  __syncthreads();
  smax[t] = m2; ssum[t] = s2;
  __syncthreads();
  for (int st = 128; st > 0; st >>= 1) {
    if (t < st) {
      float ma = smax[t], mb = smax[t + st];
      float sa = ssum[t], sb = ssum[t + st];
      float mm = fmaxf(ma, mb);
      float ss = 0.f;
      if (mm != -INFINITY)
        ss = (ma == -INFINITY ? 0.f : sa * __expf(ma - mm))
           + (mb == -INFINITY ? 0.f : sb * __expf(mb - mm));
      smax[t] = mm; ssum[t] = ss;
    }
    __syncthreads();
  }
  if (t == 0) {
    red[0] = smax[0];
    red[1] = ssum[0];
    *counter = 0;   // self-reset for next layer / replay
  }
}

// sl -> w = exp(sl - M), in place (edge-parallel: 1 exp per edge)
__global__ void k_exp2(float* __restrict__ slw, const float* __restrict__ red) {
  int e = blockIdx.x * 256 + threadIdx.x;
  if (e < N_EDGES) slw[e] = __expf(slw[e] - red[0]);
}

// ---------------- fused CSR aggregate (fp8 gather, streamed coef) + relu + LN + residual ----
__global__ void k_agg_update(const int* __restrict__ rowptr,
                             const int* __restrict__ deg,
                             const unsigned* __restrict__ packed,
                             const float* __restrict__ w,
                             const float* __restrict__ red,  // [1]=S
                             const float* __restrict__ hl,
                             const unsigned char* __restrict__ hl8,
                             const float* __restrict__ g,
                             const float* __restrict__ b,
                             float* __restrict__ h) {
  int wave = threadIdx.x >> 6, lane = threadIdx.x & 63;
  int n = blockIdx.x * 4 + wave;
  if (n >= N_NODES) return;
  int beg = rowptr[n];
  int end = beg + deg[n];
  float acc = 0.f;
  int k = beg;
  for (; k + 7 < end; k += 8) {
    unsigned u0 = packed[k],     u1 = packed[k + 1];
    unsigned u2 = packed[k + 2], u3 = packed[k + 3];
    unsigned u4 = packed[k + 4], u5 = packed[k + 5];
    unsigned u6 = packed[k + 6], u7 = packed[k + 7];
    float v0 = e42f(hl8[(size_t)(u0 >> 15) * HID + lane]);
    float v1 = e42f(hl8[(size_t)(u1 >> 15) * HID + lane]);
    float v2 = e42f(hl8[(size_t)(u2 >> 15) * HID + lane]);
    float v3 = e42f(hl8[(size_t)(u3 >> 15) * HID + lane]);
    float v4 = e42f(hl8[(size_t)(u4 >> 15) * HID + lane]);
    float v5 = e42f(hl8[(size_t)(u5 >> 15) * HID + lane]);
    float v6 = e42f(hl8[(size_t)(u6 >> 15) * HID + lane]);
    float v7 = e42f(hl8[(size_t)(u7 >> 15) * HID + lane]);
    acc += w[k] * v0 + w[k + 1] * v1 + w[k + 2] * v2 + w[k + 3] * v3
         + w[k + 4] * v4 + w[k + 5] * v5 + w[k + 6] * v6 + w[k + 7] * v7;
  }
  for (; k < end; ++k)
    acc += w[k] * e42f(hl8[(size_t)(packed[k] >> 15) * HID + lane]);

  float inv = 1.0f / red[1];
  float v = hl[(size_t)n * HID + lane] + acc * inv;
  v = fmaxf(v, 0.f);
  float m = v;
#pragma unroll
  for (int off = 32; off > 0; off >>= 1) m += __shfl_xor(m, off, 64);
  m *= (1.0f / HID);
  float d = v - m;
  float var = d * d;
#pragma unroll
  for (int off = 32; off > 0; off >>= 1) var += __shfl_xor(var, off, 64);
  var *= (1.0f / HID);
  float nv = d * rsqrtf(var + LN_EPS);
  h[(size_t)n * HID + lane] += nv * g[lane] + b[lane];
}

// ---------------- output head via MFMA ----------------
__global__ void k_out_mfma(const float* __restrict__ h,
                           const float* __restrict__ W1,  // [64][32]
                           const float* __restrict__ b1,  // [32]
                           const float* __restrict__ W2,  // [32]
                           const float* __restrict__ b2,  // [1]
                           float* __restrict__ out) {
  __shared__ unsigned short W1t[32 * 72];  // W1t[m][k] bf16
  __shared__ float sW2[32];
  for (int idx = threadIdx.x; idx < HID * 32; idx += 256) {
    int k = idx >> 5, m = idx & 31;
    W1t[m * 72 + k] = f2bf(W1[idx]);
  }
  if (threadIdx.x < 32) sW2[threadIdx.x] = W2[threadIdx.x];
  __syncthreads();

  int wave = threadIdx.x >> 6, lane = threadIdx.x & 63;
  int g = lane >> 4, r = lane & 15;
  int nb = blockIdx.x * 64 + wave * 16;
  int row = nb + r;
  bool rowok = row < N_NODES;

  f32x4 f0 = {0,0,0,0}, f1 = {0,0,0,0}, f2v = {0,0,0,0}, f3 = {0,0,0,0};
  if (rowok) {
    const float* hrow = h + (size_t)row * HID;
    f0  = *(const f32x4*)(hrow + g * 8);
    f1  = *(const f32x4*)(hrow + g * 8 + 4);
    f2v = *(const f32x4*)(hrow + 32 + g * 8);
    f3  = *(const f32x4*)(hrow + 32 + g * 8 + 4);
  }
  bf16x8 a0, a1f;
#pragma unroll
  for (int i = 0; i < 4; ++i) {
    a0[i]      = (short)f2bf(f0[i]);
    a0[i + 4]  = (short)f2bf(f1[i]);
    a1f[i]     = (short)f2bf(f2v[i]);
    a1f[i + 4] = (short)f2bf(f3[i]);
  }

  f32x4 acc[2] = {{0,0,0,0},{0,0,0,0}};
#pragma unroll
  for (int mt = 0; mt < 2; ++mt) {
    bf16x8 b0 = *(const bf16x8*)&W1t[(mt * 16 + r) * 72 + g * 8];
    bf16x8 b1v = *(const bf16x8*)&W1t[(mt * 16 + r) * 72 + 32 + g * 8];
    acc[mt] = __builtin_amdgcn_mfma_f32_16x16x32_bf16(a0, b0, acc[mt], 0, 0, 0);
    acc[mt] = __builtin_amdgcn_mfma_f32_16x16x32_bf16(a1f, b1v, acc[mt], 0, 0, 0);
  }

  float part[4];
#pragma unroll
  for (int reg = 0; reg < 4; ++reg) {
    float p = 0.f;
#pragma unroll
    for (int mt = 0; mt < 2; ++mt) {
      float z = acc[mt][reg] + b1[mt * 16 + r];
      p += fmaxf(z, 0.f) * sW2[mt * 16 + r];
    }
    p += __shfl_xor(p, 1, 64);
    p += __shfl_xor(p, 2, 64);
    p += __shfl_xor(p, 4, 64);
    p += __shfl_xor(p, 8, 64);
    part[reg] = p;
  }
  if (r == 0) {
    float bb = b2[0];
#pragma unroll
    for (int reg = 0; reg < 4; ++reg) {
      int n2 = nb + g * 4 + reg;
      if (n2 < N_NODES)
        out[n2] = 1.0f / (1.0f + expf(-(part[reg] + bb)));
    }
  }
}

extern "C" void kernel_launch(void* const* d_in, const int* in_sizes, int n_in,
                              void* d_out, int out_size, void* d_ws, size_t ws_size,
                              hipStream_t stream) {
  const float* x      = (const float*)d_in[0];
  const int*   ei     = (const int*)d_in[1];     // [2][E]
  const float* ew     = (const float*)d_in[2];
  const float* in_W   = (const float*)d_in[3];
  const float* in_b   = (const float*)d_in[4];
  const float* lin_W  = (const float*)d_in[5];   // [3][64][64]
  const float* lin_b  = (const float*)d_in[6];   // [3][64]
  const float* att_W  = (const float*)d_in[7];   // [3][128]
  const float* att_b  = (const float*)d_in[8];   // [3]
  const float* ln_g   = (const float*)d_in[9];   // [3][64]
  const float* ln_b   = (const float*)d_in[10];  // [3][64]
  const float* out1_W = (const float*)d_in[11];  // [64][32]
  const float* out1_b = (const float*)d_in[12];  // [32]
  const float* out2_W = (const float*)d_in[13];  // [32]
  const float* out2_b = (const float*)d_in[14];  // [1]
  float* out = (float*)d_out;

  float* ws = (float*)d_ws;
  float* h            = ws;                         // 6.4M f
  float* hl           = ws + 6400000;               // 6.4M f
  unsigned char* hl8  = (unsigned char*)(ws + 12800000);       // 6.4M bytes (1.6M f)
  unsigned long long* tmp = (unsigned long long*)(ws + 14500000);  // 1.25M u64
  unsigned* packed    = (unsigned*)(ws + 17000000); // 1.25M u32
  float* slw          = ws + 18250000;              // 1.25M f (scores -> coefs)
  int* deg            = (int*)(ws + 19500000);      // 100000 (+1 ticket counter)
  int* counter        = deg + N_NODES;
  int* rowptr         = (int*)(ws + 19601000);
  float* alpha1       = ws + 19702000;
  float* alpha2       = ws + 19803000;
  float* pmax         = ws + 19904000;              // 1024
  float* psum         = ws + 19906000;              // 1024
  float* red          = ws + 19908000;              // [0]=M, [1]=S
  float* uvec         = ws + 19909000;              // [3][2][64]
  float* ucst         = ws + 19910000;              // [3][2]
  int* bsum           = (int*)(ws + 19911000);      // 128
  unsigned* gbcur     = (unsigned*)(ws + 19912000); // 256

  // ---- one-time CSR build ----
  hipMemsetAsync(deg, 0, (N_NODES + 1) * sizeof(int), stream);  // deg + ticket counter
  k_hist<<<EDGE_TBLOCKS, 256, 0, stream>>>(ei, deg);
  k_blocksums<<<SCAN_BLOCKS, 1024, 0, stream>>>(deg, bsum);
  k_scan_bsums<<<1, 128, 0, stream>>>(bsum, SCAN_BLOCKS);
  k_scan_final<<<SCAN_BLOCKS, 1024, 0, stream>>>(deg, bsum, rowptr);
  k_bcur<<<1, 256, 0, stream>>>(rowptr, gbcur);
  k_fill_p1<<<P1_BLOCKS, 256, 0, stream>>>(ei, ew, gbcur, tmp);
  k_fill_p2<<<BUCKETS, 256, 0, stream>>>(rowptr, tmp, packed);

  k_prep<<<N_LAYERS, 64, 0, stream>>>(lin_W, lin_b, att_W, uvec, ucst);
  k_in_proj<<<NODE_BLOCKS, 256, 0, stream>>>(x, in_W, in_b, h);

  for (int i = 0; i < N_LAYERS; ++i) {
    k_lin_mfma<<<MFMA_BLOCKS, 256, 0, stream>>>(h, lin_W + i * HID * HID, lin_b + i * HID,
                                                uvec + i * 128, ucst + i * 2,
                                                hl, hl8, alpha1, alpha2);
    k_edge<<<NEDGE_BLOCKS, 256, 0, stream>>>(rowptr, deg, packed, alpha1, alpha2,
                                             att_b + i, slw, pmax, psum, counter, red);
    k_exp2<<<EDGE_TBLOCKS, 256, 0, stream>>>(slw, red);
    k_agg_update<<<NODE_BLOCKS, 256, 0, stream>>>(rowptr, deg, packed, slw, red,
                                                  hl, hl8, ln_g + i * HID, ln_b + i * HID, h);
  }

  k_out_mfma<<<MFMA_BLOCKS, 256, 0, stream>>>(h, out1_W, out1_b, out2_W, out2_b, out);
}

// Round 9
// 443.997 us; speedup vs baseline: 1.1032x; 1.1032x over previous
//
#include <hip/hip_runtime.h>
#include <hip/hip_fp8.h>
#include <math.h>

#define N_NODES 100000
#define N_EDGES 1250000
#define IN_DIM 12
#define HID 64
#define N_LAYERS 3
#define LN_EPS 1e-5f
#define SLOPE 0.01f

#define NODE_BLOCKS ((N_NODES + 3) / 4)     // 4 waves (nodes) per 256-thread block
#define EDGE_TBLOCKS ((N_EDGES + 255) / 256)
#define SCAN_BLOCKS ((N_NODES + 1023) / 1024)   // 98
#define MFMA_BLOCKS ((N_NODES + 63) / 64)       // 64 nodes per 256-thread block
#define NEDGE_BLOCKS ((N_NODES + 255) / 256)    // node-parallel edge pass

#define BUCKETS 256
#define BUCKET_NODES 391                         // 256*391 = 100096 >= N_NODES
#define P1_EDGES 4096
#define P1_BLOCKS ((N_EDGES + P1_EDGES - 1) / P1_EDGES)  // 306

#define LEW_SCALE 2048.0f
#define LEW_INV (1.0f / 2048.0f)

typedef short bf16x8 __attribute__((ext_vector_type(8)));
typedef float f32x4 __attribute__((ext_vector_type(4)));

static __device__ __forceinline__ unsigned short f2bf(float f) {
  union { float f; unsigned int u; } v; v.f = f;
  unsigned int r = v.u + 0x7FFFu + ((v.u >> 16) & 1u);   // RNE
  return (unsigned short)(r >> 16);
}
static __device__ __forceinline__ unsigned char f2e4(float f) {
  return __hip_fp8_e4m3(f).__x;
}
static __device__ __forceinline__ float e42f(unsigned char b) {
  __hip_fp8_e4m3 d; d.__x = b;
  return (float)d;
}

// ---------------- input projection: h = x @ in_W + in_b ----------------
__global__ void k_in_proj(const float* __restrict__ x,
                          const float* __restrict__ W,   // [12][64]
                          const float* __restrict__ b,
                          float* __restrict__ h) {
  __shared__ float sW[IN_DIM * HID];
  for (int i = threadIdx.x; i < IN_DIM * HID; i += blockDim.x) sW[i] = W[i];
  __syncthreads();
  int wave = threadIdx.x >> 6, lane = threadIdx.x & 63;
  int n = blockIdx.x * 4 + wave;
  if (n >= N_NODES) return;
  float acc = b[lane];
#pragma unroll
  for (int k = 0; k < IN_DIM; ++k)
    acc += x[n * IN_DIM + k] * sW[k * HID + lane];
  h[n * HID + lane] = acc;
}

// ---------------- CSR build (once per launch) ----------------
__global__ void k_hist(const int* __restrict__ ei, int* __restrict__ deg) {
  int e = blockIdx.x * 256 + threadIdx.x;
  if (e >= N_EDGES) return;
  atomicAdd(&deg[ei[e]], 1);
}

__global__ void k_blocksums(const int* __restrict__ deg, int* __restrict__ bsum) {
  __shared__ int sm[1024];
  int i = blockIdx.x * 1024 + threadIdx.x;
  sm[threadIdx.x] = (i < N_NODES) ? deg[i] : 0;
  __syncthreads();
  for (int st = 512; st > 0; st >>= 1) {
    if (threadIdx.x < st) sm[threadIdx.x] += sm[threadIdx.x + st];
    __syncthreads();
  }
  if (threadIdx.x == 0) bsum[blockIdx.x] = sm[0];
}

__global__ void k_scan_bsums(int* __restrict__ bsum, int nb) {  // single block, 128 thr
  __shared__ int sm[128];
  int v = (threadIdx.x < nb) ? bsum[threadIdx.x] : 0;
  sm[threadIdx.x] = v;
  __syncthreads();
  for (int st = 1; st < 128; st <<= 1) {
    int t = (threadIdx.x >= st) ? sm[threadIdx.x - st] : 0;
    __syncthreads();
    sm[threadIdx.x] += t;
    __syncthreads();
  }
  if (threadIdx.x < nb) bsum[threadIdx.x] = sm[threadIdx.x] - v;  // exclusive
}

__global__ void k_scan_final(const int* __restrict__ deg, const int* __restrict__ bsum,
                             int* __restrict__ rowptr) {
  __shared__ int sm[1024];
  int i = blockIdx.x * 1024 + threadIdx.x;
  int v = (i < N_NODES) ? deg[i] : 0;
  sm[threadIdx.x] = v;
  __syncthreads();
  for (int st = 1; st < 1024; st <<= 1) {
    int t = (threadIdx.x >= st) ? sm[threadIdx.x - st] : 0;
    __syncthreads();
    sm[threadIdx.x] += t;
    __syncthreads();
  }
  int excl = sm[threadIdx.x] - v + bsum[blockIdx.x];
  if (i < N_NODES) rowptr[i] = excl;
}

// bucket write-cursors from rowptr (bucket b covers nodes [b*391, ...))
__global__ void k_bcur(const int* __restrict__ rowptr, unsigned* __restrict__ gbcur) {
  int b = threadIdx.x;
  if (b < BUCKETS) gbcur[b] = (unsigned)rowptr[b * BUCKET_NODES];
}

// pass 1: LDS-binned burst scatter of 8B records (row|col|qlew) into bucket regions
__global__ void k_fill_p1(const int* __restrict__ ei, const float* __restrict__ ew,
                          unsigned* __restrict__ gbcur,
                          unsigned long long* __restrict__ tmp) {
  __shared__ unsigned cnt[BUCKETS], gbase[BUCKETS], lofs[BUCKETS];
  int t = threadIdx.x;
  cnt[t] = 0;
  __syncthreads();
  int base = blockIdx.x * P1_EDGES;
#pragma unroll
  for (int i = 0; i < 16; ++i) {
    int e = base + i * 256 + t;
    if (e < N_EDGES) atomicAdd(&cnt[(unsigned)ei[e] / BUCKET_NODES], 1u);
  }
  __syncthreads();
  {
    unsigned c = cnt[t];
    gbase[t] = c ? atomicAdd(&gbcur[t], c) : 0u;
    lofs[t] = 0;
  }
  __syncthreads();
#pragma unroll
  for (int i = 0; i < 16; ++i) {
    int e = base + i * 256 + t;
    if (e < N_EDGES) {
      unsigned r = (unsigned)ei[e], c = (unsigned)ei[N_EDGES + e];
      float lew = __logf(ew[e]);
      lew = fmaxf(lew, -15.9995f);
      unsigned q = (unsigned)(-lew * LEW_SCALE + 0.5f);
      if (q > 32767u) q = 32767u;
      unsigned b = r / BUCKET_NODES;
      unsigned idx = atomicAdd(&lofs[b], 1u);
      tmp[gbase[b] + idx] = ((unsigned long long)r << 32)
                          | ((unsigned long long)c << 15) | q;
    }
  }
}

// pass 2: per-bucket exact placement; scattered 4B writes stay in one ~20KB L2 window
__global__ void k_fill_p2(const int* __restrict__ rowptr,
                          const unsigned long long* __restrict__ tmp,
                          unsigned* __restrict__ packed) {
  __shared__ int lcur[BUCKET_NODES];
  int b = blockIdx.x, t = threadIdx.x;
  int nb0 = b * BUCKET_NODES;
  int nb1 = min(nb0 + BUCKET_NODES, N_NODES);
  int nn = nb1 - nb0;
  for (int j = t; j < nn; j += 256) lcur[j] = rowptr[nb0 + j];
  __syncthreads();
  int beg = rowptr[nb0];
  int end = (nb1 < N_NODES) ? rowptr[nb1] : N_EDGES;
  for (int i = beg + t; i < end; i += 256) {
    unsigned long long rec = tmp[i];
    int r = (int)(rec >> 32);
    int pos = atomicAdd(&lcur[r - nb0], 1);
    packed[pos] = (unsigned)(rec & 0xFFFFFFFFu);
  }
}

// ---------------- per-layer u = W @ a  (alpha decomposition) ----------------
__global__ void k_prep(const float* __restrict__ lin_W,  // [3][64][64]
                       const float* __restrict__ lin_b,  // [3][64]
                       const float* __restrict__ att_W,  // [3][128]
                       float* __restrict__ uvec,         // [3][2][64]
                       float* __restrict__ ucst) {       // [3][2]
  int l = blockIdx.x, j = threadIdx.x;
  const float* Wl = lin_W + l * HID * HID;
  const float* a1 = att_W + l * 2 * HID;
  const float* a2 = a1 + HID;
  float s1 = 0.f, s2 = 0.f;
  for (int c = 0; c < HID; ++c) {
    float w = Wl[j * HID + c];
    s1 += w * a1[c];
    s2 += w * a2[c];
  }
  uvec[l * 128 + j] = s1;
  uvec[l * 128 + 64 + j] = s2;
  float t1 = lin_b[l * HID + j] * a1[j];
  float t2 = lin_b[l * HID + j] * a2[j];
#pragma unroll
  for (int off = 32; off > 0; off >>= 1) {
    t1 += __shfl_xor(t1, off, 64);
    t2 += __shfl_xor(t2, off, 64);
  }
  if (j == 0) { ucst[l * 2] = t1; ucst[l * 2 + 1] = t2; }
}

// ---------------- MFMA linear: hl = h@W + b (fp32 + fp8 mirror); alphas ----------------
__global__ void k_lin_mfma(const float* __restrict__ h,
                           const float* __restrict__ W,     // [64][64] this layer
                           const float* __restrict__ bias,  // [64]
                           const float* __restrict__ uvec,  // [2][64] this layer
                           const float* __restrict__ ucst,  // [2]
                           float* __restrict__ hl,
                           unsigned char* __restrict__ hl8, // fp8 e4m3 mirror
                           float* __restrict__ alpha1,
                           float* __restrict__ alpha2) {
  __shared__ unsigned short Wt[HID * 72];  // Wt[n][k] bf16, row stride 72
  for (int idx = threadIdx.x; idx < HID * HID; idx += 256) {
    int k = idx >> 6, n = idx & 63;
    Wt[n * 72 + k] = f2bf(W[idx]);
  }
  __syncthreads();

  int wave = threadIdx.x >> 6, lane = threadIdx.x & 63;
  int g = lane >> 4, r = lane & 15;
  int nb = blockIdx.x * 64 + wave * 16;
  int row = nb + r;
  bool rowok = row < N_NODES;

  f32x4 f0 = {0,0,0,0}, f1 = {0,0,0,0}, f2v = {0,0,0,0}, f3 = {0,0,0,0};
  if (rowok) {
    const float* hrow = h + (size_t)row * HID;
    f0  = *(const f32x4*)(hrow + g * 8);
    f1  = *(const f32x4*)(hrow + g * 8 + 4);
    f2v = *(const f32x4*)(hrow + 32 + g * 8);
    f3  = *(const f32x4*)(hrow + 32 + g * 8 + 4);
  }
  bf16x8 a0, a1f;
#pragma unroll
  for (int i = 0; i < 4; ++i) {
    a0[i]      = (short)f2bf(f0[i]);
    a0[i + 4]  = (short)f2bf(f1[i]);
    a1f[i]     = (short)f2bf(f2v[i]);
    a1f[i + 4] = (short)f2bf(f3[i]);
  }

  f32x4 acc[4] = {{0,0,0,0},{0,0,0,0},{0,0,0,0},{0,0,0,0}};
#pragma unroll
  for (int nt = 0; nt < 4; ++nt) {
    bf16x8 b0 = *(const bf16x8*)&Wt[(nt * 16 + r) * 72 + g * 8];
    bf16x8 b1 = *(const bf16x8*)&Wt[(nt * 16 + r) * 72 + 32 + g * 8];
    acc[nt] = __builtin_amdgcn_mfma_f32_16x16x32_bf16(a0, b0, acc[nt], 0, 0, 0);
    acc[nt] = __builtin_amdgcn_mfma_f32_16x16x32_bf16(a1f, b1, acc[nt], 0, 0, 0);
  }

  // alphas from fp32 h fragments
  {
    const float* u1 = uvec;
    const float* u2 = uvec + HID;
    f32x4 ua = *(const f32x4*)(u1 + g * 8),      ub = *(const f32x4*)(u1 + g * 8 + 4);
    f32x4 uc = *(const f32x4*)(u1 + 32 + g * 8), ud = *(const f32x4*)(u1 + 32 + g * 8 + 4);
    float p1 = f0[0]*ua[0]+f0[1]*ua[1]+f0[2]*ua[2]+f0[3]*ua[3]
             + f1[0]*ub[0]+f1[1]*ub[1]+f1[2]*ub[2]+f1[3]*ub[3]
             + f2v[0]*uc[0]+f2v[1]*uc[1]+f2v[2]*uc[2]+f2v[3]*uc[3]
             + f3[0]*ud[0]+f3[1]*ud[1]+f3[2]*ud[2]+f3[3]*ud[3];
    ua = *(const f32x4*)(u2 + g * 8);      ub = *(const f32x4*)(u2 + g * 8 + 4);
    uc = *(const f32x4*)(u2 + 32 + g * 8); ud = *(const f32x4*)(u2 + 32 + g * 8 + 4);
    float p2 = f0[0]*ua[0]+f0[1]*ua[1]+f0[2]*ua[2]+f0[3]*ua[3]
             + f1[0]*ub[0]+f1[1]*ub[1]+f1[2]*ub[2]+f1[3]*ub[3]
             + f2v[0]*uc[0]+f2v[1]*uc[1]+f2v[2]*uc[2]+f2v[3]*uc[3]
             + f3[0]*ud[0]+f3[1]*ud[1]+f3[2]*ud[2]+f3[3]*ud[3];
    p1 += __shfl_xor(p1, 16, 64); p1 += __shfl_xor(p1, 32, 64);
    p2 += __shfl_xor(p2, 16, 64); p2 += __shfl_xor(p2, 32, 64);
    if (g == 0 && rowok) {
      alpha1[row] = p1 + ucst[0];
      alpha2[row] = p2 + ucst[1];
    }
  }

  // store hl (+bias) fp32 + fp8 mirror. D: col = nt*16 + r, node = nb + g*4 + reg
#pragma unroll
  for (int nt = 0; nt < 4; ++nt) {
    float bv = bias[nt * 16 + r];
#pragma unroll
    for (int reg = 0; reg < 4; ++reg) {
      int n2 = nb + g * 4 + reg;
      if (n2 < N_NODES) {
        float v = acc[nt][reg] + bv;
        hl[(size_t)n2 * HID + nt * 16 + r] = v;
        hl8[(size_t)n2 * HID + nt * 16 + r] = f2e4(v);
      }
    }
  }
}

// ---------------- per-layer edge pass (node-parallel) + fused ticket combine ----------------
__global__ void k_edge(const int* __restrict__ rowptr,
                       const int* __restrict__ deg,
                       const unsigned* __restrict__ packed,
                       const float* __restrict__ alpha1,
                       const float* __restrict__ alpha2,
                       const float* __restrict__ attB,
                       float* __restrict__ slw,
                       float* __restrict__ pmax,
                       float* __restrict__ psum,
                       int* __restrict__ counter,
                       float* __restrict__ red) {
  int t = threadIdx.x;
  int n = blockIdx.x * 256 + t;
  float m = -INFINITY, sum = 0.f;
  if (n < N_NODES) {
    float a1 = alpha1[n] + attB[0];
    int beg = rowptr[n];
    int end = beg + deg[n];
    for (int p = beg; p < end; ++p) {
      unsigned u = packed[p];
      float sc = a1 + alpha2[u >> 15];
      sc = sc > 0.f ? sc : SLOPE * sc;
      slw[p] = sc - (float)(u & 0x7FFFu) * LEW_INV;
      if (sc > m) { sum *= __expf(m - sc); m = sc; }
      sum += __expf(sc - m);
    }
  }
  __shared__ float smax[256], ssum[256];
  __shared__ bool last;
  smax[t] = m; ssum[t] = sum;
  __syncthreads();
  for (int st = 128; st > 0; st >>= 1) {
    if (t < st) {
      float ma = smax[t], mb = smax[t + st];
      float sa = ssum[t], sb = ssum[t + st];
      float mm = fmaxf(ma, mb);
      float ss = 0.f;
      if (mm != -INFINITY)
        ss = (ma == -INFINITY ? 0.f : sa * __expf(ma - mm))
           + (mb == -INFINITY ? 0.f : sb * __expf(mb - mm));
      smax[t] = mm; ssum[t] = ss;
    }
    __syncthreads();
  }
  if (t == 0) {
    pmax[blockIdx.x] = smax[0];
    psum[blockIdx.x] = ssum[0];
    __threadfence();
    int old = atomicAdd(counter, 1);
    last = (old == (int)gridDim.x - 1);
  }
  __syncthreads();
  if (!last) return;
  __threadfence();
  volatile const float* vpm = pmax;
  volatile const float* vps = psum;
  float m2 = -INFINITY, s2 = 0.f;
  for (int i = t; i < (int)gridDim.x; i += 256) {
    float mb = vpm[i], sb = vps[i];
    if (mb != -INFINITY) {
      if (mb > m2) { s2 *= __expf(m2 - mb); m2 = mb; }
      s2 += sb * __expf(mb - m2);
    }
  }
  __syncthreads();
  smax[t] = m2; ssum[t] = s2;
  __syncthreads();
  for (int st = 128; st > 0; st >>= 1) {
    if (t < st) {
      float ma = smax[t], mb = smax[t + st];
      float sa = ssum[t], sb = ssum[t + st];
      float mm = fmaxf(ma, mb);
      float ss = 0.f;
      if (mm != -INFINITY)
        ss = (ma == -INFINITY ? 0.f : sa * __expf(ma - mm))
           + (mb == -INFINITY ? 0.f : sb * __expf(mb - mm));
      smax[t] = mm; ssum[t] = ss;
    }
    __syncthreads();
  }
  if (t == 0) {
    red[0] = smax[0];
    red[1] = ssum[0];
    *counter = 0;   // self-reset for next layer / replay
  }
}

// sl -> w = exp(sl - M), in place (edge-parallel: 1 exp per edge)
__global__ void k_exp2(float* __restrict__ slw, const float* __restrict__ red) {
  int e = blockIdx.x * 256 + threadIdx.x;
  if (e < N_EDGES) slw[e] = __expf(slw[e] - red[0]);
}

// ---------------- fused CSR aggregate: 4-edge x 16-lane layout + relu + LN + residual ----
// lane = g*16 + q : edge-subgroup g in [0,4), quarter-row q in [0,16) -> channels q*4..q*4+3
__global__ void k_agg_update(const int* __restrict__ rowptr,
                             const int* __restrict__ deg,
                             const unsigned* __restrict__ packed,
                             const float* __restrict__ w,
                             const float* __restrict__ red,  // [1]=S
                             const float* __restrict__ hl,
                             const unsigned char* __restrict__ hl8,
                             const float* __restrict__ gam,
                             const float* __restrict__ bet,
                             float* __restrict__ h) {
  int wave = threadIdx.x >> 6, lane = threadIdx.x & 63;
  int n = blockIdx.x * 4 + wave;
  if (n >= N_NODES) return;
  int g = lane >> 4, q = lane & 15;
  int beg = rowptr[n];
  int end = beg + deg[n];

  float a0 = 0.f, a1 = 0.f, a2 = 0.f, a3 = 0.f;
  for (int k = beg; k < end; k += 8) {
    int ke0 = k + g, ke1 = k + 4 + g;
    bool v0 = ke0 < end, v1 = ke1 < end;
    unsigned u0 = packed[v0 ? ke0 : beg];
    unsigned u1 = packed[v1 ? ke1 : beg];
    float w0 = v0 ? w[ke0] : 0.f;
    float w1 = v1 ? w[ke1] : 0.f;
    unsigned d0 = *(const unsigned*)(hl8 + (size_t)(u0 >> 15) * HID + q * 4);
    unsigned d1 = *(const unsigned*)(hl8 + (size_t)(u1 >> 15) * HID + q * 4);
    a0 += w0 * e42f(d0 & 0xffu)         + w1 * e42f(d1 & 0xffu);
    a1 += w0 * e42f((d0 >> 8) & 0xffu)  + w1 * e42f((d1 >> 8) & 0xffu);
    a2 += w0 * e42f((d0 >> 16) & 0xffu) + w1 * e42f((d1 >> 16) & 0xffu);
    a3 += w0 * e42f(d0 >> 24)           + w1 * e42f(d1 >> 24);
  }
  // fold edge-subgroups (bits 4,5 of lane)
  a0 += __shfl_xor(a0, 16, 64); a0 += __shfl_xor(a0, 32, 64);
  a1 += __shfl_xor(a1, 16, 64); a1 += __shfl_xor(a1, 32, 64);
  a2 += __shfl_xor(a2, 16, 64); a2 += __shfl_xor(a2, 32, 64);
  a3 += __shfl_xor(a3, 16, 64); a3 += __shfl_xor(a3, 32, 64);

  float inv = 1.0f / red[1];
  const float* hlrow = hl + (size_t)n * HID + q * 4;
  float v0 = fmaxf(hlrow[0] + a0 * inv, 0.f);
  float v1 = fmaxf(hlrow[1] + a1 * inv, 0.f);
  float v2 = fmaxf(hlrow[2] + a2 * inv, 0.f);
  float v3 = fmaxf(hlrow[3] + a3 * inv, 0.f);

  float ms = v0 + v1 + v2 + v3;
  ms += __shfl_xor(ms, 1, 64); ms += __shfl_xor(ms, 2, 64);
  ms += __shfl_xor(ms, 4, 64); ms += __shfl_xor(ms, 8, 64);
  float m = ms * (1.0f / HID);
  float d0 = v0 - m, d1 = v1 - m, d2 = v2 - m, d3 = v3 - m;
  float vs = d0 * d0 + d1 * d1 + d2 * d2 + d3 * d3;
  vs += __shfl_xor(vs, 1, 64); vs += __shfl_xor(vs, 2, 64);
  vs += __shfl_xor(vs, 4, 64); vs += __shfl_xor(vs, 8, 64);
  float rs = rsqrtf(vs * (1.0f / HID) + LN_EPS);

  if (g == 0) {
    float* hrow = h + (size_t)n * HID + q * 4;
    f32x4 hv = *(const f32x4*)hrow;
    f32x4 gv = *(const f32x4*)(gam + q * 4);
    f32x4 bv = *(const f32x4*)(bet + q * 4);
    f32x4 o;
    o[0] = hv[0] + d0 * rs * gv[0] + bv[0];
    o[1] = hv[1] + d1 * rs * gv[1] + bv[1];
    o[2] = hv[2] + d2 * rs * gv[2] + bv[2];
    o[3] = hv[3] + d3 * rs * gv[3] + bv[3];
    *(f32x4*)hrow = o;
  }
}

// ---------------- output head via MFMA ----------------
__global__ void k_out_mfma(const float* __restrict__ h,
                           const float* __restrict__ W1,  // [64][32]
                           const float* __restrict__ b1,  // [32]
                           const float* __restrict__ W2,  // [32]
                           const float* __restrict__ b2,  // [1]
                           float* __restrict__ out) {
  __shared__ unsigned short W1t[32 * 72];  // W1t[m][k] bf16
  __shared__ float sW2[32];
  for (int idx = threadIdx.x; idx < HID * 32; idx += 256) {
    int k = idx >> 5, m = idx & 31;
    W1t[m * 72 + k] = f2bf(W1[idx]);
  }
  if (threadIdx.x < 32) sW2[threadIdx.x] = W2[threadIdx.x];
  __syncthreads();

  int wave = threadIdx.x >> 6, lane = threadIdx.x & 63;
  int g = lane >> 4, r = lane & 15;
  int nb = blockIdx.x * 64 + wave * 16;
  int row = nb + r;
  bool rowok = row < N_NODES;

  f32x4 f0 = {0,0,0,0}, f1 = {0,0,0,0}, f2v = {0,0,0,0}, f3 = {0,0,0,0};
  if (rowok) {
    const float* hrow = h + (size_t)row * HID;
    f0  = *(const f32x4*)(hrow + g * 8);
    f1  = *(const f32x4*)(hrow + g * 8 + 4);
    f2v = *(const f32x4*)(hrow + 32 + g * 8);
    f3  = *(const f32x4*)(hrow + 32 + g * 8 + 4);
  }
  bf16x8 a0, a1f;
#pragma unroll
  for (int i = 0; i < 4; ++i) {
    a0[i]      = (short)f2bf(f0[i]);
    a0[i + 4]  = (short)f2bf(f1[i]);
    a1f[i]     = (short)f2bf(f2v[i]);
    a1f[i + 4] = (short)f2bf(f3[i]);
  }

  f32x4 acc[2] = {{0,0,0,0},{0,0,0,0}};
#pragma unroll
  for (int mt = 0; mt < 2; ++mt) {
    bf16x8 b0 = *(const bf16x8*)&W1t[(mt * 16 + r) * 72 + g * 8];
    bf16x8 b1v = *(const bf16x8*)&W1t[(mt * 16 + r) * 72 + 32 + g * 8];
    acc[mt] = __builtin_amdgcn_mfma_f32_16x16x32_bf16(a0, b0, acc[mt], 0, 0, 0);
    acc[mt] = __builtin_amdgcn_mfma_f32_16x16x32_bf16(a1f, b1v, acc[mt], 0, 0, 0);
  }

  float part[4];
#pragma unroll
  for (int reg = 0; reg < 4; ++reg) {
    float p = 0.f;
#pragma unroll
    for (int mt = 0; mt < 2; ++mt) {
      float z = acc[mt][reg] + b1[mt * 16 + r];
      p += fmaxf(z, 0.f) * sW2[mt * 16 + r];
    }
    p += __shfl_xor(p, 1, 64);
    p += __shfl_xor(p, 2, 64);
    p += __shfl_xor(p, 4, 64);
    p += __shfl_xor(p, 8, 64);
    part[reg] = p;
  }
  if (r == 0) {
    float bb = b2[0];
#pragma unroll
    for (int reg = 0; reg < 4; ++reg) {
      int n2 = nb + g * 4 + reg;
      if (n2 < N_NODES)
        out[n2] = 1.0f / (1.0f + expf(-(part[reg] + bb)));
    }
  }
}

extern "C" void kernel_launch(void* const* d_in, const int* in_sizes, int n_in,
                              void* d_out, int out_size, void* d_ws, size_t ws_size,
                              hipStream_t stream) {
  const float* x      = (const float*)d_in[0];
  const int*   ei     = (const int*)d_in[1];     // [2][E]
  const float* ew     = (const float*)d_in[2];
  const float* in_W   = (const float*)d_in[3];
  const float* in_b   = (const float*)d_in[4];
  const float* lin_W  = (const float*)d_in[5];   // [3][64][64]
  const float* lin_b  = (const float*)d_in[6];   // [3][64]
  const float* att_W  = (const float*)d_in[7];   // [3][128]
  const float* att_b  = (const float*)d_in[8];   // [3]
  const float* ln_g   = (const float*)d_in[9];   // [3][64]
  const float* ln_b   = (const float*)d_in[10];  // [3][64]
  const float* out1_W = (const float*)d_in[11];  // [64][32]
  const float* out1_b = (const float*)d_in[12];  // [32]
  const float* out2_W = (const float*)d_in[13];  // [32]
  const float* out2_b = (const float*)d_in[14];  // [1]
  float* out = (float*)d_out;

  float* ws = (float*)d_ws;
  float* h            = ws;                         // 6.4M f
  float* hl           = ws + 6400000;               // 6.4M f
  unsigned char* hl8  = (unsigned char*)(ws + 12800000);       // 6.4M bytes (1.6M f)
  unsigned long long* tmp = (unsigned long long*)(ws + 14500000);  // 1.25M u64
  unsigned* packed    = (unsigned*)(ws + 17000000); // 1.25M u32
  float* slw          = ws + 18250000;              // 1.25M f (scores -> coefs)
  int* deg            = (int*)(ws + 19500000);      // 100000 (+1 ticket counter)
  int* counter        = deg + N_NODES;
  int* rowptr         = (int*)(ws + 19601000);
  float* alpha1       = ws + 19702000;
  float* alpha2       = ws + 19803000;
  float* pmax         = ws + 19904000;              // 1024
  float* psum         = ws + 19906000;              // 1024
  float* red          = ws + 19908000;              // [0]=M, [1]=S
  float* uvec         = ws + 19909000;              // [3][2][64]
  float* ucst         = ws + 19910000;              // [3][2]
  int* bsum           = (int*)(ws + 19911000);      // 128
  unsigned* gbcur     = (unsigned*)(ws + 19912000); // 256

  // ---- one-time CSR build ----
  hipMemsetAsync(deg, 0, (N_NODES + 1) * sizeof(int), stream);  // deg + ticket counter
  k_hist<<<EDGE_TBLOCKS, 256, 0, stream>>>(ei, deg);
  k_blocksums<<<SCAN_BLOCKS, 1024, 0, stream>>>(deg, bsum);
  k_scan_bsums<<<1, 128, 0, stream>>>(bsum, SCAN_BLOCKS);
  k_scan_final<<<SCAN_BLOCKS, 1024, 0, stream>>>(deg, bsum, rowptr);
  k_bcur<<<1, 256, 0, stream>>>(rowptr, gbcur);
  k_fill_p1<<<P1_BLOCKS, 256, 0, stream>>>(ei, ew, gbcur, tmp);
  k_fill_p2<<<BUCKETS, 256, 0, stream>>>(rowptr, tmp, packed);

  k_prep<<<N_LAYERS, 64, 0, stream>>>(lin_W, lin_b, att_W, uvec, ucst);
  k_in_proj<<<NODE_BLOCKS, 256, 0, stream>>>(x, in_W, in_b, h);

  for (int i = 0; i < N_LAYERS; ++i) {
    k_lin_mfma<<<MFMA_BLOCKS, 256, 0, stream>>>(h, lin_W + i * HID * HID, lin_b + i * HID,
                                                uvec + i * 128, ucst + i * 2,
                                                hl, hl8, alpha1, alpha2);
    k_edge<<<NEDGE_BLOCKS, 256, 0, stream>>>(rowptr, deg, packed, alpha1, alpha2,
                                             att_b + i, slw, pmax, psum, counter, red);
    k_exp2<<<EDGE_TBLOCKS, 256, 0, stream>>>(slw, red);
    k_agg_update<<<NODE_BLOCKS, 256, 0, stream>>>(rowptr, deg, packed, slw, red,
                                                  hl, hl8, ln_g + i * HID, ln_b + i * HID, h);
  }

  k_out_mfma<<<MFMA_BLOCKS, 256, 0, stream>>>(h, out1_W, out1_b, out2_W, out2_b, out);
}

// Round 10
// 430.895 us; speedup vs baseline: 1.1367x; 1.0304x over previous
//
#include <hip/hip_runtime.h>
#include <hip/hip_fp8.h>
#include <math.h>

#define N_NODES 100000
#define N_EDGES 1250000
#define IN_DIM 12
#define HID 64
#define N_LAYERS 3
#define LN_EPS 1e-5f
#define SLOPE 0.01f

#define NODE_BLOCKS ((N_NODES + 3) / 4)     // 4 waves (nodes) per 256-thread block
#define EDGE_TBLOCKS ((N_EDGES + 255) / 256)
#define SCAN_BLOCKS ((N_NODES + 1023) / 1024)   // 98
#define MFMA_BLOCKS2 ((N_NODES + 127) / 128)    // 128 nodes per 256-thread block (2 tiles)
#define OUT_BLOCKS ((N_NODES + 63) / 64)
#define NEDGE_BLOCKS ((N_NODES + 255) / 256)    // node-parallel edge pass

#define BUCKETS 256
#define BUCKET_NODES 391                         // 256*391 = 100096 >= N_NODES
#define P1_EDGES 4096
#define P1_BLOCKS ((N_EDGES + P1_EDGES - 1) / P1_EDGES)  // 306

#define LEW_SCALE 2048.0f
#define LEW_INV (1.0f / 2048.0f)

typedef short bf16x8 __attribute__((ext_vector_type(8)));
typedef float f32x4 __attribute__((ext_vector_type(4)));
typedef float f32x2 __attribute__((ext_vector_type(2)));

#if defined(__has_builtin)
#if __has_builtin(__builtin_amdgcn_cvt_pk_f32_fp8)
#define HAVE_PK_FP8 1
#endif
#endif

static __device__ __forceinline__ unsigned short f2bf(float f) {
  union { float f; unsigned int u; } v; v.f = f;
  unsigned int r = v.u + 0x7FFFu + ((v.u >> 16) & 1u);   // RNE
  return (unsigned short)(r >> 16);
}
static __device__ __forceinline__ unsigned char f2e4(float f) {
  return __hip_fp8_e4m3(f).__x;
}
static __device__ __forceinline__ float e42f(unsigned char b) {
  __hip_fp8_e4m3 d; d.__x = b;
  return (float)d;
}

// ---------------- input projection: h = x @ in_W + in_b ----------------
__global__ void k_in_proj(const float* __restrict__ x,
                          const float* __restrict__ W,   // [12][64]
                          const float* __restrict__ b,
                          float* __restrict__ h) {
  __shared__ float sW[IN_DIM * HID];
  for (int i = threadIdx.x; i < IN_DIM * HID; i += blockDim.x) sW[i] = W[i];
  __syncthreads();
  int wave = threadIdx.x >> 6, lane = threadIdx.x & 63;
  int n = blockIdx.x * 4 + wave;
  if (n >= N_NODES) return;
  float acc = b[lane];
#pragma unroll
  for (int k = 0; k < IN_DIM; ++k)
    acc += x[n * IN_DIM + k] * sW[k * HID + lane];
  h[n * HID + lane] = acc;
}

// ---------------- CSR build (once per launch) ----------------
__global__ void k_hist(const int* __restrict__ ei, int* __restrict__ deg) {
  int e = blockIdx.x * 256 + threadIdx.x;
  if (e >= N_EDGES) return;
  atomicAdd(&deg[ei[e]], 1);
}

__global__ void k_blocksums(const int* __restrict__ deg, int* __restrict__ bsum) {
  __shared__ int sm[1024];
  int i = blockIdx.x * 1024 + threadIdx.x;
  sm[threadIdx.x] = (i < N_NODES) ? deg[i] : 0;
  __syncthreads();
  for (int st = 512; st > 0; st >>= 1) {
    if (threadIdx.x < st) sm[threadIdx.x] += sm[threadIdx.x + st];
    __syncthreads();
  }
  if (threadIdx.x == 0) bsum[blockIdx.x] = sm[0];
}

__global__ void k_scan_bsums(int* __restrict__ bsum, int nb) {  // single block, 128 thr
  __shared__ int sm[128];
  int v = (threadIdx.x < nb) ? bsum[threadIdx.x] : 0;
  sm[threadIdx.x] = v;
  __syncthreads();
  for (int st = 1; st < 128; st <<= 1) {
    int t = (threadIdx.x >= st) ? sm[threadIdx.x - st] : 0;
    __syncthreads();
    sm[threadIdx.x] += t;
    __syncthreads();
  }
  if (threadIdx.x < nb) bsum[threadIdx.x] = sm[threadIdx.x] - v;  // exclusive
}

__global__ void k_scan_final(const int* __restrict__ deg, const int* __restrict__ bsum,
                             int* __restrict__ rowptr, unsigned* __restrict__ gbcur) {
  __shared__ int sm[1024];
  int i = blockIdx.x * 1024 + threadIdx.x;
  int v = (i < N_NODES) ? deg[i] : 0;
  sm[threadIdx.x] = v;
  __syncthreads();
  for (int st = 1; st < 1024; st <<= 1) {
    int t = (threadIdx.x >= st) ? sm[threadIdx.x - st] : 0;
    __syncthreads();
    sm[threadIdx.x] += t;
    __syncthreads();
  }
  int excl = sm[threadIdx.x] - v + bsum[blockIdx.x];
  if (i < N_NODES) {
    rowptr[i] = excl;
    int bb = i / BUCKET_NODES;
    if (i - bb * BUCKET_NODES == 0) gbcur[bb] = (unsigned)excl;  // fused k_bcur
  }
}

// pass 1: LDS-binned burst scatter of 8B records (row|col|qlew) into bucket regions
__global__ void k_fill_p1(const int* __restrict__ ei, const float* __restrict__ ew,
                          unsigned* __restrict__ gbcur,
                          unsigned long long* __restrict__ tmp) {
  __shared__ unsigned cnt[BUCKETS], gbase[BUCKETS], lofs[BUCKETS];
  int t = threadIdx.x;
  cnt[t] = 0;
  __syncthreads();
  int base = blockIdx.x * P1_EDGES;
#pragma unroll
  for (int i = 0; i < 16; ++i) {
    int e = base + i * 256 + t;
    if (e < N_EDGES) atomicAdd(&cnt[(unsigned)ei[e] / BUCKET_NODES], 1u);
  }
  __syncthreads();
  {
    unsigned c = cnt[t];
    gbase[t] = c ? atomicAdd(&gbcur[t], c) : 0u;
    lofs[t] = 0;
  }
  __syncthreads();
#pragma unroll
  for (int i = 0; i < 16; ++i) {
    int e = base + i * 256 + t;
    if (e < N_EDGES) {
      unsigned r = (unsigned)ei[e], c = (unsigned)ei[N_EDGES + e];
      float lew = __logf(ew[e]);
      lew = fmaxf(lew, -15.9995f);
      unsigned q = (unsigned)(-lew * LEW_SCALE + 0.5f);
      if (q > 32767u) q = 32767u;
      unsigned b = r / BUCKET_NODES;
      unsigned idx = atomicAdd(&lofs[b], 1u);
      tmp[gbase[b] + idx] = ((unsigned long long)r << 32)
                          | ((unsigned long long)c << 15) | q;
    }
  }
}

// pass 2: per-bucket exact placement; scattered 4B writes stay in one ~20KB L2 window
__global__ void k_fill_p2(const int* __restrict__ rowptr,
                          const unsigned long long* __restrict__ tmp,
                          unsigned* __restrict__ packed) {
  __shared__ int lcur[BUCKET_NODES];
  int b = blockIdx.x, t = threadIdx.x;
  int nb0 = b * BUCKET_NODES;
  int nb1 = min(nb0 + BUCKET_NODES, N_NODES);
  int nn = nb1 - nb0;
  for (int j = t; j < nn; j += 256) lcur[j] = rowptr[nb0 + j];
  __syncthreads();
  int beg = rowptr[nb0];
  int end = (nb1 < N_NODES) ? rowptr[nb1] : N_EDGES;
  for (int i = beg + t; i < end; i += 256) {
    unsigned long long rec = tmp[i];
    int r = (int)(rec >> 32);
    int pos = atomicAdd(&lcur[r - nb0], 1);
    packed[pos] = (unsigned)(rec & 0xFFFFFFFFu);
  }
}

// ---------------- per-layer u = W @ a  (alpha decomposition) ----------------
__global__ void k_prep(const float* __restrict__ lin_W,  // [3][64][64]
                       const float* __restrict__ lin_b,  // [3][64]
                       const float* __restrict__ att_W,  // [3][128]
                       float* __restrict__ uvec,         // [3][2][64]
                       float* __restrict__ ucst) {       // [3][2]
  int l = blockIdx.x, j = threadIdx.x;
  const float* Wl = lin_W + l * HID * HID;
  const float* a1 = att_W + l * 2 * HID;
  const float* a2 = a1 + HID;
  float s1 = 0.f, s2 = 0.f;
  for (int c = 0; c < HID; ++c) {
    float w = Wl[j * HID + c];
    s1 += w * a1[c];
    s2 += w * a2[c];
  }
  uvec[l * 128 + j] = s1;
  uvec[l * 128 + 64 + j] = s2;
  float t1 = lin_b[l * HID + j] * a1[j];
  float t2 = lin_b[l * HID + j] * a2[j];
#pragma unroll
  for (int off = 32; off > 0; off >>= 1) {
    t1 += __shfl_xor(t1, off, 64);
    t2 += __shfl_xor(t2, off, 64);
  }
  if (j == 0) { ucst[l * 2] = t1; ucst[l * 2 + 1] = t2; }
}

// ---------------- MFMA linear: hl = h@W + b (fp32 + fp8 mirror); alphas ----------------
// 2 x 64-node tiles per block, reusing staged W
__global__ void k_lin_mfma(const float* __restrict__ h,
                           const float* __restrict__ W,     // [64][64] this layer
                           const float* __restrict__ bias,  // [64]
                           const float* __restrict__ uvec,  // [2][64] this layer
                           const float* __restrict__ ucst,  // [2]
                           float* __restrict__ hl,
                           unsigned char* __restrict__ hl8, // fp8 e4m3 mirror
                           float* __restrict__ alpha1,
                           float* __restrict__ alpha2) {
  __shared__ unsigned short Wt[HID * 72];  // Wt[n][k] bf16, row stride 72
  for (int idx = threadIdx.x; idx < HID * HID; idx += 256) {
    int k = idx >> 6, n = idx & 63;
    Wt[n * 72 + k] = f2bf(W[idx]);
  }
  __syncthreads();

  int wave = threadIdx.x >> 6, lane = threadIdx.x & 63;
  int g = lane >> 4, r = lane & 15;

#pragma unroll
  for (int tile = 0; tile < 2; ++tile) {
    int nb = blockIdx.x * 128 + tile * 64 + wave * 16;
    int row = nb + r;
    bool rowok = row < N_NODES;
    if (nb >= N_NODES) break;

    f32x4 f0 = {0,0,0,0}, f1 = {0,0,0,0}, f2v = {0,0,0,0}, f3 = {0,0,0,0};
    if (rowok) {
      const float* hrow = h + (size_t)row * HID;
      f0  = *(const f32x4*)(hrow + g * 8);
      f1  = *(const f32x4*)(hrow + g * 8 + 4);
      f2v = *(const f32x4*)(hrow + 32 + g * 8);
      f3  = *(const f32x4*)(hrow + 32 + g * 8 + 4);
    }
    bf16x8 a0, a1f;
#pragma unroll
    for (int i = 0; i < 4; ++i) {
      a0[i]      = (short)f2bf(f0[i]);
      a0[i + 4]  = (short)f2bf(f1[i]);
      a1f[i]     = (short)f2bf(f2v[i]);
      a1f[i + 4] = (short)f2bf(f3[i]);
    }

    f32x4 acc[4] = {{0,0,0,0},{0,0,0,0},{0,0,0,0},{0,0,0,0}};
#pragma unroll
    for (int nt = 0; nt < 4; ++nt) {
      bf16x8 b0 = *(const bf16x8*)&Wt[(nt * 16 + r) * 72 + g * 8];
      bf16x8 b1 = *(const bf16x8*)&Wt[(nt * 16 + r) * 72 + 32 + g * 8];
      acc[nt] = __builtin_amdgcn_mfma_f32_16x16x32_bf16(a0, b0, acc[nt], 0, 0, 0);
      acc[nt] = __builtin_amdgcn_mfma_f32_16x16x32_bf16(a1f, b1, acc[nt], 0, 0, 0);
    }

    // alphas from fp32 h fragments
    {
      const float* u1 = uvec;
      const float* u2 = uvec + HID;
      f32x4 ua = *(const f32x4*)(u1 + g * 8),      ub = *(const f32x4*)(u1 + g * 8 + 4);
      f32x4 uc = *(const f32x4*)(u1 + 32 + g * 8), ud = *(const f32x4*)(u1 + 32 + g * 8 + 4);
      float p1 = f0[0]*ua[0]+f0[1]*ua[1]+f0[2]*ua[2]+f0[3]*ua[3]
               + f1[0]*ub[0]+f1[1]*ub[1]+f1[2]*ub[2]+f1[3]*ub[3]
               + f2v[0]*uc[0]+f2v[1]*uc[1]+f2v[2]*uc[2]+f2v[3]*uc[3]
               + f3[0]*ud[0]+f3[1]*ud[1]+f3[2]*ud[2]+f3[3]*ud[3];
      ua = *(const f32x4*)(u2 + g * 8);      ub = *(const f32x4*)(u2 + g * 8 + 4);
      uc = *(const f32x4*)(u2 + 32 + g * 8); ud = *(const f32x4*)(u2 + 32 + g * 8 + 4);
      float p2 = f0[0]*ua[0]+f0[1]*ua[1]+f0[2]*ua[2]+f0[3]*ua[3]
               + f1[0]*ub[0]+f1[1]*ub[1]+f1[2]*ub[2]+f1[3]*ub[3]
               + f2v[0]*uc[0]+f2v[1]*uc[1]+f2v[2]*uc[2]+f2v[3]*uc[3]
               + f3[0]*ud[0]+f3[1]*ud[1]+f3[2]*ud[2]+f3[3]*ud[3];
      p1 += __shfl_xor(p1, 16, 64); p1 += __shfl_xor(p1, 32, 64);
      p2 += __shfl_xor(p2, 16, 64); p2 += __shfl_xor(p2, 32, 64);
      if (g == 0 && rowok) {
        alpha1[row] = p1 + ucst[0];
        alpha2[row] = p2 + ucst[1];
      }
    }

    // store hl (+bias) fp32 + fp8 mirror. D: col = nt*16 + r, node = nb + g*4 + reg
#pragma unroll
    for (int nt = 0; nt < 4; ++nt) {
      float bv = bias[nt * 16 + r];
#pragma unroll
      for (int reg = 0; reg < 4; ++reg) {
        int n2 = nb + g * 4 + reg;
        if (n2 < N_NODES) {
          float v = acc[nt][reg] + bv;
          hl[(size_t)n2 * HID + nt * 16 + r] = v;
          hl8[(size_t)n2 * HID + nt * 16 + r] = f2e4(v);
        }
      }
    }
  }
}

// ---------------- per-layer edge pass (node-parallel) + fused ticket combine ----------------
__global__ void k_edge(const int* __restrict__ rowptr,
                       const int* __restrict__ deg,
                       const unsigned* __restrict__ packed,
                       const float* __restrict__ alpha1,
                       const float* __restrict__ alpha2,
                       const float* __restrict__ attB,
                       float* __restrict__ slw,
                       float* __restrict__ pmax,
                       float* __restrict__ psum,
                       int* __restrict__ counter,
                       float* __restrict__ red) {
  int t = threadIdx.x;
  int n = blockIdx.x * 256 + t;
  float m = -INFINITY, sum = 0.f;
  if (n < N_NODES) {
    float a1 = alpha1[n] + attB[0];
    int beg = rowptr[n];
    int end = beg + deg[n];
    for (int p = beg; p < end; ++p) {
      unsigned u = packed[p];
      float sc = a1 + alpha2[u >> 15];
      sc = sc > 0.f ? sc : SLOPE * sc;
      slw[p] = sc - (float)(u & 0x7FFFu) * LEW_INV;
      if (sc > m) { sum *= __expf(m - sc); m = sc; }
      sum += __expf(sc - m);
    }
  }
  __shared__ float smax[256], ssum[256];
  __shared__ bool last;
  smax[t] = m; ssum[t] = sum;
  __syncthreads();
  for (int st = 128; st > 0; st >>= 1) {
    if (t < st) {
      float ma = smax[t], mb = smax[t + st];
      float sa = ssum[t], sb = ssum[t + st];
      float mm = fmaxf(ma, mb);
      float ss = 0.f;
      if (mm != -INFINITY)
        ss = (ma == -INFINITY ? 0.f : sa * __expf(ma - mm))
           + (mb == -INFINITY ? 0.f : sb * __expf(mb - mm));
      smax[t] = mm; ssum[t] = ss;
    }
    __syncthreads();
  }
  if (t == 0) {
    pmax[blockIdx.x] = smax[0];
    psum[blockIdx.x] = ssum[0];
    __threadfence();
    int old = atomicAdd(counter, 1);
    last = (old == (int)gridDim.x - 1);
  }
  __syncthreads();
  if (!last) return;
  __threadfence();
  volatile const float* vpm = pmax;
  volatile const float* vps = psum;
  float m2 = -INFINITY, s2 = 0.f;
  for (int i = t; i < (int)gridDim.x; i += 256) {
    float mb = vpm[i], sb = vps[i];
    if (mb != -INFINITY) {
      if (mb > m2) { s2 *= __expf(m2 - mb); m2 = mb; }
      s2 += sb * __expf(mb - m2);
    }
  }
  __syncthreads();
  smax[t] = m2; ssum[t] = s2;
  __syncthreads();
  for (int st = 128; st > 0; st >>= 1) {
    if (t < st) {
      float ma = smax[t], mb = smax[t + st];
      float sa = ssum[t], sb = ssum[t + st];
      float mm = fmaxf(ma, mb);
      float ss = 0.f;
      if (mm != -INFINITY)
        ss = (ma == -INFINITY ? 0.f : sa * __expf(ma - mm))
           + (mb == -INFINITY ? 0.f : sb * __expf(mb - mm));
      smax[t] = mm; ssum[t] = ss;
    }
    __syncthreads();
  }
  if (t == 0) {
    red[0] = smax[0];
    red[1] = ssum[0];
    *counter = 0;   // self-reset for next layer / replay
  }
}

// sl -> w = exp(sl - M), in place, x4 vectorized
__global__ void k_exp2(f32x4* __restrict__ slw, const float* __restrict__ red) {
  int i = blockIdx.x * 256 + threadIdx.x;
  int nvec = (N_EDGES + 3) / 4;
  if (i >= nvec) return;
  float M = red[0];
  f32x4 v = slw[i];
  v[0] = __expf(v[0] - M);
  v[1] = __expf(v[1] - M);
  v[2] = __expf(v[2] - M);
  v[3] = __expf(v[3] - M);
  slw[i] = v;
}

// ---------------- fused CSR aggregate: 16-edge x 16-lane layout + relu + LN + residual ----
// lane = g*16 + q : edge-subgroup g in [0,4), quarter-row q in [0,16) -> channels q*4..q*4+3
__global__ void k_agg_update(const int* __restrict__ rowptr,
                             const int* __restrict__ deg,
                             const unsigned* __restrict__ packed,
                             const float* __restrict__ w,
                             const float* __restrict__ red,  // [1]=S
                             const float* __restrict__ hl,
                             const unsigned char* __restrict__ hl8,
                             const float* __restrict__ gam,
                             const float* __restrict__ bet,
                             float* __restrict__ h) {
  int wave = threadIdx.x >> 6, lane = threadIdx.x & 63;
  int n = blockIdx.x * 4 + wave;
  if (n >= N_NODES) return;
  int g = lane >> 4, q = lane & 15;
  int beg = rowptr[n];
  int end = beg + deg[n];

  float a0 = 0.f, a1 = 0.f, a2 = 0.f, a3 = 0.f;
  for (int k = beg; k < end; k += 16) {
    int ke0 = k + g, ke1 = k + 4 + g, ke2 = k + 8 + g, ke3 = k + 12 + g;
    bool v0 = ke0 < end, v1 = ke1 < end, v2 = ke2 < end, v3 = ke3 < end;
    unsigned u0 = packed[v0 ? ke0 : beg];
    unsigned u1 = packed[v1 ? ke1 : beg];
    unsigned u2 = packed[v2 ? ke2 : beg];
    unsigned u3 = packed[v3 ? ke3 : beg];
    float w0 = v0 ? w[ke0] : 0.f;
    float w1 = v1 ? w[ke1] : 0.f;
    float w2 = v2 ? w[ke2] : 0.f;
    float w3 = v3 ? w[ke3] : 0.f;
    unsigned d0 = *(const unsigned*)(hl8 + (size_t)(u0 >> 15) * HID + q * 4);
    unsigned d1 = *(const unsigned*)(hl8 + (size_t)(u1 >> 15) * HID + q * 4);
    unsigned d2 = *(const unsigned*)(hl8 + (size_t)(u2 >> 15) * HID + q * 4);
    unsigned d3 = *(const unsigned*)(hl8 + (size_t)(u3 >> 15) * HID + q * 4);
#ifdef HAVE_PK_FP8
    f32x2 l0 = __builtin_amdgcn_cvt_pk_f32_fp8((int)d0, 0);
    f32x2 h0 = __builtin_amdgcn_cvt_pk_f32_fp8((int)d0, 1);
    f32x2 l1 = __builtin_amdgcn_cvt_pk_f32_fp8((int)d1, 0);
    f32x2 h1 = __builtin_amdgcn_cvt_pk_f32_fp8((int)d1, 1);
    f32x2 l2 = __builtin_amdgcn_cvt_pk_f32_fp8((int)d2, 0);
    f32x2 h2 = __builtin_amdgcn_cvt_pk_f32_fp8((int)d2, 1);
    f32x2 l3 = __builtin_amdgcn_cvt_pk_f32_fp8((int)d3, 0);
    f32x2 h3 = __builtin_amdgcn_cvt_pk_f32_fp8((int)d3, 1);
    a0 += w0 * l0[0] + w1 * l1[0] + w2 * l2[0] + w3 * l3[0];
    a1 += w0 * l0[1] + w1 * l1[1] + w2 * l2[1] + w3 * l3[1];
    a2 += w0 * h0[0] + w1 * h1[0] + w2 * h2[0] + w3 * h3[0];
    a3 += w0 * h0[1] + w1 * h1[1] + w2 * h2[1] + w3 * h3[1];
#else
    a0 += w0 * e42f(d0 & 0xffu) + w1 * e42f(d1 & 0xffu)
        + w2 * e42f(d2 & 0xffu) + w3 * e42f(d3 & 0xffu);
    a1 += w0 * e42f((d0 >> 8) & 0xffu) + w1 * e42f((d1 >> 8) & 0xffu)
        + w2 * e42f((d2 >> 8) & 0xffu) + w3 * e42f((d3 >> 8) & 0xffu);
    a2 += w0 * e42f((d0 >> 16) & 0xffu) + w1 * e42f((d1 >> 16) & 0xffu)
        + w2 * e42f((d2 >> 16) & 0xffu) + w3 * e42f((d3 >> 16) & 0xffu);
    a3 += w0 * e42f(d0 >> 24) + w1 * e42f(d1 >> 24)
        + w2 * e42f(d2 >> 24) + w3 * e42f(d3 >> 24);
#endif
  }
  // fold edge-subgroups (bits 4,5 of lane)
  a0 += __shfl_xor(a0, 16, 64); a0 += __shfl_xor(a0, 32, 64);
  a1 += __shfl_xor(a1, 16, 64); a1 += __shfl_xor(a1, 32, 64);
  a2 += __shfl_xor(a2, 16, 64); a2 += __shfl_xor(a2, 32, 64);
  a3 += __shfl_xor(a3, 16, 64); a3 += __shfl_xor(a3, 32, 64);

  float inv = 1.0f / red[1];
  const float* hlrow = hl + (size_t)n * HID + q * 4;
  float v0 = fmaxf(hlrow[0] + a0 * inv, 0.f);
  float v1 = fmaxf(hlrow[1] + a1 * inv, 0.f);
  float v2 = fmaxf(hlrow[2] + a2 * inv, 0.f);
  float v3 = fmaxf(hlrow[3] + a3 * inv, 0.f);

  float ms = v0 + v1 + v2 + v3;
  ms += __shfl_xor(ms, 1, 64); ms += __shfl_xor(ms, 2, 64);
  ms += __shfl_xor(ms, 4, 64); ms += __shfl_xor(ms, 8, 64);
  float m = ms * (1.0f / HID);
  float d0 = v0 - m, d1 = v1 - m, d2 = v2 - m, d3 = v3 - m;
  float vs = d0 * d0 + d1 * d1 + d2 * d2 + d3 * d3;
  vs += __shfl_xor(vs, 1, 64); vs += __shfl_xor(vs, 2, 64);
  vs += __shfl_xor(vs, 4, 64); vs += __shfl_xor(vs, 8, 64);
  float rs = rsqrtf(vs * (1.0f / HID) + LN_EPS);

  if (g == 0) {
    float* hrow = h + (size_t)n * HID + q * 4;
    f32x4 hv = *(const f32x4*)hrow;
    f32x4 gv = *(const f32x4*)(gam + q * 4);
    f32x4 bv = *(const f32x4*)(bet + q * 4);
    f32x4 o;
    o[0] = hv[0] + d0 * rs * gv[0] + bv[0];
    o[1] = hv[1] + d1 * rs * gv[1] + bv[1];
    o[2] = hv[2] + d2 * rs * gv[2] + bv[2];
    o[3] = hv[3] + d3 * rs * gv[3] + bv[3];
    *(f32x4*)hrow = o;
  }
}

// ---------------- output head via MFMA ----------------
__global__ void k_out_mfma(const float* __restrict__ h,
                           const float* __restrict__ W1,  // [64][32]
                           const float* __restrict__ b1,  // [32]
                           const float* __restrict__ W2,  // [32]
                           const float* __restrict__ b2,  // [1]
                           float* __restrict__ out) {
  __shared__ unsigned short W1t[32 * 72];  // W1t[m][k] bf16
  __shared__ float sW2[32];
  for (int idx = threadIdx.x; idx < HID * 32; idx += 256) {
    int k = idx >> 5, m = idx & 31;
    W1t[m * 72 + k] = f2bf(W1[idx]);
  }
  if (threadIdx.x < 32) sW2[threadIdx.x] = W2[threadIdx.x];
  __syncthreads();

  int wave = threadIdx.x >> 6, lane = threadIdx.x & 63;
  int g = lane >> 4, r = lane & 15;
  int nb = blockIdx.x * 64 + wave * 16;
  int row = nb + r;
  bool rowok = row < N_NODES;

  f32x4 f0 = {0,0,0,0}, f1 = {0,0,0,0}, f2v = {0,0,0,0}, f3 = {0,0,0,0};
  if (rowok) {
    const float* hrow = h + (size_t)row * HID;
    f0  = *(const f32x4*)(hrow + g * 8);
    f1  = *(const f32x4*)(hrow + g * 8 + 4);
    f2v = *(const f32x4*)(hrow + 32 + g * 8);
    f3  = *(const f32x4*)(hrow + 32 + g * 8 + 4);
  }
  bf16x8 a0, a1f;
#pragma unroll
  for (int i = 0; i < 4; ++i) {
    a0[i]      = (short)f2bf(f0[i]);
    a0[i + 4]  = (short)f2bf(f1[i]);
    a1f[i]     = (short)f2bf(f2v[i]);
    a1f[i + 4] = (short)f2bf(f3[i]);
  }

  f32x4 acc[2] = {{0,0,0,0},{0,0,0,0}};
#pragma unroll
  for (int mt = 0; mt < 2; ++mt) {
    bf16x8 b0 = *(const bf16x8*)&W1t[(mt * 16 + r) * 72 + g * 8];
    bf16x8 b1v = *(const bf16x8*)&W1t[(mt * 16 + r) * 72 + 32 + g * 8];
    acc[mt] = __builtin_amdgcn_mfma_f32_16x16x32_bf16(a0, b0, acc[mt], 0, 0, 0);
    acc[mt] = __builtin_amdgcn_mfma_f32_16x16x32_bf16(a1f, b1v, acc[mt], 0, 0, 0);
  }

  float part[4];
#pragma unroll
  for (int reg = 0; reg < 4; ++reg) {
    float p = 0.f;
#pragma unroll
    for (int mt = 0; mt < 2; ++mt) {
      float z = acc[mt][reg] + b1[mt * 16 + r];
      p += fmaxf(z, 0.f) * sW2[mt * 16 + r];
    }
    p += __shfl_xor(p, 1, 64);
    p += __shfl_xor(p, 2, 64);
    p += __shfl_xor(p, 4, 64);
    p += __shfl_xor(p, 8, 64);
    part[reg] = p;
  }
  if (r == 0) {
    float bb = b2[0];
#pragma unroll
    for (int reg = 0; reg < 4; ++reg) {
      int n2 = nb + g * 4 + reg;
      if (n2 < N_NODES)
        out[n2] = 1.0f / (1.0f + expf(-(part[reg] + bb)));
    }
  }
}

extern "C" void kernel_launch(void* const* d_in, const int* in_sizes, int n_in,
                              void* d_out, int out_size, void* d_ws, size_t ws_size,
                              hipStream_t stream) {
  const float* x      = (const float*)d_in[0];
  const int*   ei     = (const int*)d_in[1];     // [2][E]
  const float* ew     = (const float*)d_in[2];
  const float* in_W   = (const float*)d_in[3];
  const float* in_b   = (const float*)d_in[4];
  const float* lin_W  = (const float*)d_in[5];   // [3][64][64]
  const float* lin_b  = (const float*)d_in[6];   // [3][64]
  const float* att_W  = (const float*)d_in[7];   // [3][128]
  const float* att_b  = (const float*)d_in[8];   // [3]
  const float* ln_g   = (const float*)d_in[9];   // [3][64]
  const float* ln_b   = (const float*)d_in[10];  // [3][64]
  const float* out1_W = (const float*)d_in[11];  // [64][32]
  const float* out1_b = (const float*)d_in[12];  // [32]
  const float* out2_W = (const float*)d_in[13];  // [32]
  const float* out2_b = (const float*)d_in[14];  // [1]
  float* out = (float*)d_out;

  float* ws = (float*)d_ws;
  float* h            = ws;                         // 6.4M f
  float* hl           = ws + 6400000;               // 6.4M f
  unsigned char* hl8  = (unsigned char*)(ws + 12800000);       // 6.4M bytes (1.6M f)
  unsigned long long* tmp = (unsigned long long*)(ws + 14500000);  // 1.25M u64
  unsigned* packed    = (unsigned*)(ws + 17000000); // 1.25M u32
  float* slw          = ws + 18250000;              // 1.25M f (scores -> coefs); 16B-aligned
  int* deg            = (int*)(ws + 19500000);      // 100000 (+1 ticket counter)
  int* counter        = deg + N_NODES;
  int* rowptr         = (int*)(ws + 19601000);
  float* alpha1       = ws + 19702000;
  float* alpha2       = ws + 19803000;
  float* pmax         = ws + 19904000;              // 1024
  float* psum         = ws + 19906000;              // 1024
  float* red          = ws + 19908000;              // [0]=M, [1]=S
  float* uvec         = ws + 19909000;              // [3][2][64]
  float* ucst         = ws + 19910000;              // [3][2]
  int* bsum           = (int*)(ws + 19911000);      // 128
  unsigned* gbcur     = (unsigned*)(ws + 19912000); // 256

  // ---- one-time CSR build ----
  hipMemsetAsync(deg, 0, (N_NODES + 1) * sizeof(int), stream);  // deg + ticket counter
  k_hist<<<EDGE_TBLOCKS, 256, 0, stream>>>(ei, deg);
  k_blocksums<<<SCAN_BLOCKS, 1024, 0, stream>>>(deg, bsum);
  k_scan_bsums<<<1, 128, 0, stream>>>(bsum, SCAN_BLOCKS);
  k_scan_final<<<SCAN_BLOCKS, 1024, 0, stream>>>(deg, bsum, rowptr, gbcur);
  k_fill_p1<<<P1_BLOCKS, 256, 0, stream>>>(ei, ew, gbcur, tmp);
  k_fill_p2<<<BUCKETS, 256, 0, stream>>>(rowptr, tmp, packed);

  k_prep<<<N_LAYERS, 64, 0, stream>>>(lin_W, lin_b, att_W, uvec, ucst);
  k_in_proj<<<NODE_BLOCKS, 256, 0, stream>>>(x, in_W, in_b, h);

  for (int i = 0; i < N_LAYERS; ++i) {
    k_lin_mfma<<<MFMA_BLOCKS2, 256, 0, stream>>>(h, lin_W + i * HID * HID, lin_b + i * HID,
                                                 uvec + i * 128, ucst + i * 2,
                                                 hl, hl8, alpha1, alpha2);
    k_edge<<<NEDGE_BLOCKS, 256, 0, stream>>>(rowptr, deg, packed, alpha1, alpha2,
                                             att_b + i, slw, pmax, psum, counter, red);
    k_exp2<<<(((N_EDGES + 3) / 4) + 255) / 256, 256, 0, stream>>>((f32x4*)slw, red);
    k_agg_update<<<NODE_BLOCKS, 256, 0, stream>>>(rowptr, deg, packed, slw, red,
                                                  hl, hl8, ln_g + i * HID, ln_b + i * HID, h);
  }

  k_out_mfma<<<OUT_BLOCKS, 256, 0, stream>>>(h, out1_W, out1_b, out2_W, out2_b, out);
}

// Round 11
// 375.174 us; speedup vs baseline: 1.3055x; 1.1485x over previous
//
#include <hip/hip_runtime.h>
#include <hip/hip_fp8.h>
#include <math.h>

#define N_NODES 100000
#define N_EDGES 1250000
#define IN_DIM 12
#define HID 64
#define N_LAYERS 3
#define LN_EPS 1e-5f
#define SLOPE 0.01f

#define NODE_BLOCKS ((N_NODES + 3) / 4)     // 4 waves (nodes) per 256-thread block
#define EDGE_TBLOCKS ((N_EDGES + 255) / 256)
#define MFMA_BLOCKS2 ((N_NODES + 127) / 128)    // 128 nodes per 256-thread block (2 tiles)
#define OUT_BLOCKS ((N_NODES + 63) / 64)
#define NEDGE_BLOCKS ((N_NODES + 255) / 256)    // node-parallel edge pass

#define BUCKETS 256
#define BUCKET_NODES 391                         // 256*391 = 100096 >= N_NODES
#define P1_EDGES 4096
#define P1_BLOCKS ((N_EDGES + P1_EDGES - 1) / P1_EDGES)  // 306

#define LEW_SCALE 2048.0f
#define LEW_INV (1.0f / 2048.0f)

typedef short bf16x8 __attribute__((ext_vector_type(8)));
typedef float f32x4 __attribute__((ext_vector_type(4)));
typedef float f32x2 __attribute__((ext_vector_type(2)));

#if defined(__has_builtin)
#if __has_builtin(__builtin_amdgcn_cvt_pk_f32_fp8)
#define HAVE_PK_FP8 1
#endif
#endif

static __device__ __forceinline__ unsigned short f2bf(float f) {
  union { float f; unsigned int u; } v; v.f = f;
  unsigned int r = v.u + 0x7FFFu + ((v.u >> 16) & 1u);   // RNE
  return (unsigned short)(r >> 16);
}
static __device__ __forceinline__ unsigned char f2e4(float f) {
  return __hip_fp8_e4m3(f).__x;
}
static __device__ __forceinline__ float e42f(unsigned char b) {
  __hip_fp8_e4m3 d; d.__x = b;
  return (float)d;
}

// ---------------- input projection: h = x @ in_W + in_b ----------------
__global__ void k_in_proj(const float* __restrict__ x,
                          const float* __restrict__ W,   // [12][64]
                          const float* __restrict__ b,
                          float* __restrict__ h) {
  __shared__ float sW[IN_DIM * HID];
  for (int i = threadIdx.x; i < IN_DIM * HID; i += blockDim.x) sW[i] = W[i];
  __syncthreads();
  int wave = threadIdx.x >> 6, lane = threadIdx.x & 63;
  int n = blockIdx.x * 4 + wave;
  if (n >= N_NODES) return;
  float acc = b[lane];
#pragma unroll
  for (int k = 0; k < IN_DIM; ++k)
    acc += x[n * IN_DIM + k] * sW[k * HID + lane];
  h[n * HID + lane] = acc;
}

// ---------------- bucket-level histogram (LDS; 256 global atomics per block) ----------------
__global__ void k_bhist(const int* __restrict__ ei, unsigned* __restrict__ bcnt) {
  __shared__ unsigned cnt[BUCKETS];
  int t = threadIdx.x;
  cnt[t] = 0;
  __syncthreads();
  int base = blockIdx.x * P1_EDGES;
#pragma unroll
  for (int i = 0; i < 16; ++i) {
    int e = base + i * 256 + t;
    if (e < N_EDGES) atomicAdd(&cnt[(unsigned)ei[e] / BUCKET_NODES], 1u);
  }
  __syncthreads();
  if (cnt[t]) atomicAdd(&bcnt[t], cnt[t]);
}

// 1-block scan of bucket counts -> boffs[257]; seed gbcur; rowptr sentinel
__global__ void k_bscan(const unsigned* __restrict__ bcnt,
                        unsigned* __restrict__ boffs,
                        unsigned* __restrict__ gbcur,
                        int* __restrict__ rowptr) {
  __shared__ unsigned sm[BUCKETS];
  int t = threadIdx.x;
  unsigned v = bcnt[t];
  sm[t] = v;
  __syncthreads();
  for (int st = 1; st < BUCKETS; st <<= 1) {
    unsigned tv = (t >= st) ? sm[t - st] : 0u;
    __syncthreads();
    sm[t] += tv;
    __syncthreads();
  }
  unsigned excl = sm[t] - v;
  boffs[t] = excl;
  gbcur[t] = excl;
  if (t == 0) {
    boffs[BUCKETS] = N_EDGES;
    rowptr[N_NODES] = N_EDGES;
  }
}

// pass 1: LDS-binned burst scatter of 8B records (row|col|qlew) into bucket regions
__global__ void k_fill_p1(const int* __restrict__ ei, const float* __restrict__ ew,
                          unsigned* __restrict__ gbcur,
                          unsigned long long* __restrict__ tmp) {
  __shared__ unsigned cnt[BUCKETS], gbase[BUCKETS], lofs[BUCKETS];
  int t = threadIdx.x;
  cnt[t] = 0;
  __syncthreads();
  int base = blockIdx.x * P1_EDGES;
#pragma unroll
  for (int i = 0; i < 16; ++i) {
    int e = base + i * 256 + t;
    if (e < N_EDGES) atomicAdd(&cnt[(unsigned)ei[e] / BUCKET_NODES], 1u);
  }
  __syncthreads();
  {
    unsigned c = cnt[t];
    gbase[t] = c ? atomicAdd(&gbcur[t], c) : 0u;
    lofs[t] = 0;
  }
  __syncthreads();
#pragma unroll
  for (int i = 0; i < 16; ++i) {
    int e = base + i * 256 + t;
    if (e < N_EDGES) {
      unsigned r = (unsigned)ei[e], c = (unsigned)ei[N_EDGES + e];
      float lew = __logf(ew[e]);
      lew = fmaxf(lew, -15.9995f);
      unsigned q = (unsigned)(-lew * LEW_SCALE + 0.5f);
      if (q > 32767u) q = 32767u;
      unsigned b = r / BUCKET_NODES;
      unsigned idx = atomicAdd(&lofs[b], 1u);
      tmp[gbase[b] + idx] = ((unsigned long long)r << 32)
                          | ((unsigned long long)c << 15) | q;
    }
  }
}

// pass 2 (512 thr): per-bucket node histogram + scan -> rowptr; exact placement of records
__global__ void k_fill_p2(const unsigned* __restrict__ boffs,
                          const unsigned long long* __restrict__ tmp,
                          int* __restrict__ rowptr,
                          unsigned* __restrict__ packed) {
  __shared__ unsigned lhist[512];
  __shared__ unsigned lcur[512];
  int b = blockIdx.x, t = threadIdx.x;
  int nb0 = b * BUCKET_NODES;
  int nb1 = min(nb0 + BUCKET_NODES, N_NODES);
  int nn = nb1 - nb0;
  int beg = (int)boffs[b];
  int end = (int)boffs[b + 1];

  lhist[t] = 0;
  __syncthreads();
  for (int i = beg + t; i < end; i += 512) {
    int r = (int)(tmp[i] >> 32);
    atomicAdd(&lhist[r - nb0], 1u);
  }
  __syncthreads();
  unsigned degv = lhist[t];
  // inclusive Hillis-Steele scan over 512 slots
  for (int st = 1; st < 512; st <<= 1) {
    unsigned tv = (t >= st) ? lhist[t - st] : 0u;
    __syncthreads();
    lhist[t] += tv;
    __syncthreads();
  }
  unsigned excl = lhist[t] - degv;
  if (t < nn) rowptr[nb0 + t] = beg + (int)excl;
  lcur[t] = (unsigned)beg + excl;
  __syncthreads();
  for (int i = beg + t; i < end; i += 512) {
    unsigned long long rec = tmp[i];
    int r = (int)(rec >> 32);
    unsigned pos = atomicAdd(&lcur[r - nb0], 1u);
    packed[pos] = (unsigned)(rec & 0xFFFFFFFFu);
  }
}

// ---------------- per-layer u = W @ a  (alpha decomposition) ----------------
__global__ void k_prep(const float* __restrict__ lin_W,  // [3][64][64]
                       const float* __restrict__ lin_b,  // [3][64]
                       const float* __restrict__ att_W,  // [3][128]
                       float* __restrict__ uvec,         // [3][2][64]
                       float* __restrict__ ucst) {       // [3][2]
  int l = blockIdx.x, j = threadIdx.x;
  const float* Wl = lin_W + l * HID * HID;
  const float* a1 = att_W + l * 2 * HID;
  const float* a2 = a1 + HID;
  float s1 = 0.f, s2 = 0.f;
  for (int c = 0; c < HID; ++c) {
    float w = Wl[j * HID + c];
    s1 += w * a1[c];
    s2 += w * a2[c];
  }
  uvec[l * 128 + j] = s1;
  uvec[l * 128 + 64 + j] = s2;
  float t1 = lin_b[l * HID + j] * a1[j];
  float t2 = lin_b[l * HID + j] * a2[j];
#pragma unroll
  for (int off = 32; off > 0; off >>= 1) {
    t1 += __shfl_xor(t1, off, 64);
    t2 += __shfl_xor(t2, off, 64);
  }
  if (j == 0) { ucst[l * 2] = t1; ucst[l * 2 + 1] = t2; }
}

// ---------------- MFMA linear: hl = h@W + b (fp32 + fp8 mirror); alphas ----------------
// 2 x 64-node tiles per block, reusing staged W
__global__ void k_lin_mfma(const float* __restrict__ h,
                           const float* __restrict__ W,     // [64][64] this layer
                           const float* __restrict__ bias,  // [64]
                           const float* __restrict__ uvec,  // [2][64] this layer
                           const float* __restrict__ ucst,  // [2]
                           float* __restrict__ hl,
                           unsigned char* __restrict__ hl8, // fp8 e4m3 mirror
                           float* __restrict__ alpha1,
                           float* __restrict__ alpha2) {
  __shared__ unsigned short Wt[HID * 72];  // Wt[n][k] bf16, row stride 72
  for (int idx = threadIdx.x; idx < HID * HID; idx += 256) {
    int k = idx >> 6, n = idx & 63;
    Wt[n * 72 + k] = f2bf(W[idx]);
  }
  __syncthreads();

  int wave = threadIdx.x >> 6, lane = threadIdx.x & 63;
  int g = lane >> 4, r = lane & 15;

#pragma unroll
  for (int tile = 0; tile < 2; ++tile) {
    int nb = blockIdx.x * 128 + tile * 64 + wave * 16;
    int row = nb + r;
    bool rowok = row < N_NODES;
    if (nb >= N_NODES) break;

    f32x4 f0 = {0,0,0,0}, f1 = {0,0,0,0}, f2v = {0,0,0,0}, f3 = {0,0,0,0};
    if (rowok) {
      const float* hrow = h + (size_t)row * HID;
      f0  = *(const f32x4*)(hrow + g * 8);
      f1  = *(const f32x4*)(hrow + g * 8 + 4);
      f2v = *(const f32x4*)(hrow + 32 + g * 8);
      f3  = *(const f32x4*)(hrow + 32 + g * 8 + 4);
    }
    bf16x8 a0, a1f;
#pragma unroll
    for (int i = 0; i < 4; ++i) {
      a0[i]      = (short)f2bf(f0[i]);
      a0[i + 4]  = (short)f2bf(f1[i]);
      a1f[i]     = (short)f2bf(f2v[i]);
      a1f[i + 4] = (short)f2bf(f3[i]);
    }

    f32x4 acc[4] = {{0,0,0,0},{0,0,0,0},{0,0,0,0},{0,0,0,0}};
#pragma unroll
    for (int nt = 0; nt < 4; ++nt) {
      bf16x8 b0 = *(const bf16x8*)&Wt[(nt * 16 + r) * 72 + g * 8];
      bf16x8 b1 = *(const bf16x8*)&Wt[(nt * 16 + r) * 72 + 32 + g * 8];
      acc[nt] = __builtin_amdgcn_mfma_f32_16x16x32_bf16(a0, b0, acc[nt], 0, 0, 0);
      acc[nt] = __builtin_amdgcn_mfma_f32_16x16x32_bf16(a1f, b1, acc[nt], 0, 0, 0);
    }

    // alphas from fp32 h fragments
    {
      const float* u1 = uvec;
      const float* u2 = uvec + HID;
      f32x4 ua = *(const f32x4*)(u1 + g * 8),      ub = *(const f32x4*)(u1 + g * 8 + 4);
      f32x4 uc = *(const f32x4*)(u1 + 32 + g * 8), ud = *(const f32x4*)(u1 + 32 + g * 8 + 4);
      float p1 = f0[0]*ua[0]+f0[1]*ua[1]+f0[2]*ua[2]+f0[3]*ua[3]
               + f1[0]*ub[0]+f1[1]*ub[1]+f1[2]*ub[2]+f1[3]*ub[3]
               + f2v[0]*uc[0]+f2v[1]*uc[1]+f2v[2]*uc[2]+f2v[3]*uc[3]
               + f3[0]*ud[0]+f3[1]*ud[1]+f3[2]*ud[2]+f3[3]*ud[3];
      ua = *(const f32x4*)(u2 + g * 8);      ub = *(const f32x4*)(u2 + g * 8 + 4);
      uc = *(const f32x4*)(u2 + 32 + g * 8); ud = *(const f32x4*)(u2 + 32 + g * 8 + 4);
      float p2 = f0[0]*ua[0]+f0[1]*ua[1]+f0[2]*ua[2]+f0[3]*ua[3]
               + f1[0]*ub[0]+f1[1]*ub[1]+f1[2]*ub[2]+f1[3]*ub[3]
               + f2v[0]*uc[0]+f2v[1]*uc[1]+f2v[2]*uc[2]+f2v[3]*uc[3]
               + f3[0]*ud[0]+f3[1]*ud[1]+f3[2]*ud[2]+f3[3]*ud[3];
      p1 += __shfl_xor(p1, 16, 64); p1 += __shfl_xor(p1, 32, 64);
      p2 += __shfl_xor(p2, 16, 64); p2 += __shfl_xor(p2, 32, 64);
      if (g == 0 && rowok) {
        alpha1[row] = p1 + ucst[0];
        alpha2[row] = p2 + ucst[1];
      }
    }

    // store hl (+bias) fp32 + fp8 mirror. D: col = nt*16 + r, node = nb + g*4 + reg
#pragma unroll
    for (int nt = 0; nt < 4; ++nt) {
      float bv = bias[nt * 16 + r];
#pragma unroll
      for (int reg = 0; reg < 4; ++reg) {
        int n2 = nb + g * 4 + reg;
        if (n2 < N_NODES) {
          float v = acc[nt][reg] + bv;
          hl[(size_t)n2 * HID + nt * 16 + r] = v;
          hl8[(size_t)n2 * HID + nt * 16 + r] = f2e4(v);
        }
      }
    }
  }
}

// ---------------- per-layer edge pass (node-parallel) + fused ticket combine ----------------
__global__ void k_edge(const int* __restrict__ rowptr,
                       const unsigned* __restrict__ packed,
                       const float* __restrict__ alpha1,
                       const float* __restrict__ alpha2,
                       const float* __restrict__ attB,
                       float* __restrict__ slw,
                       float* __restrict__ pmax,
                       float* __restrict__ psum,
                       int* __restrict__ counter,
                       float* __restrict__ red) {
  int t = threadIdx.x;
  int n = blockIdx.x * 256 + t;
  float m = -INFINITY, sum = 0.f;
  if (n < N_NODES) {
    float a1 = alpha1[n] + attB[0];
    int beg = rowptr[n];
    int end = rowptr[n + 1];
    for (int p = beg; p < end; ++p) {
      unsigned u = packed[p];
      float sc = a1 + alpha2[u >> 15];
      sc = sc > 0.f ? sc : SLOPE * sc;
      slw[p] = sc - (float)(u & 0x7FFFu) * LEW_INV;
      if (sc > m) { sum *= __expf(m - sc); m = sc; }
      sum += __expf(sc - m);
    }
  }
  __shared__ float smax[256], ssum[256];
  __shared__ bool last;
  smax[t] = m; ssum[t] = sum;
  __syncthreads();
  for (int st = 128; st > 0; st >>= 1) {
    if (t < st) {
      float ma = smax[t], mb = smax[t + st];
      float sa = ssum[t], sb = ssum[t + st];
      float mm = fmaxf(ma, mb);
      float ss = 0.f;
      if (mm != -INFINITY)
        ss = (ma == -INFINITY ? 0.f : sa * __expf(ma - mm))
           + (mb == -INFINITY ? 0.f : sb * __expf(mb - mm));
      smax[t] = mm; ssum[t] = ss;
    }
    __syncthreads();
  }
  if (t == 0) {
    pmax[blockIdx.x] = smax[0];
    psum[blockIdx.x] = ssum[0];
    __threadfence();
    int old = atomicAdd(counter, 1);
    last = (old == (int)gridDim.x - 1);
  }
  __syncthreads();
  if (!last) return;
  __threadfence();
  volatile const float* vpm = pmax;
  volatile const float* vps = psum;
  float m2 = -INFINITY, s2 = 0.f;
  for (int i = t; i < (int)gridDim.x; i += 256) {
    float mb = vpm[i], sb = vps[i];
    if (mb != -INFINITY) {
      if (mb > m2) { s2 *= __expf(m2 - mb); m2 = mb; }
      s2 += sb * __expf(mb - m2);
    }
  }
  __syncthreads();
  smax[t] = m2; ssum[t] = s2;
  __syncthreads();
  for (int st = 128; st > 0; st >>= 1) {
    if (t < st) {
      float ma = smax[t], mb = smax[t + st];
      float sa = ssum[t], sb = ssum[t + st];
      float mm = fmaxf(ma, mb);
      float ss = 0.f;
      if (mm != -INFINITY)
        ss = (ma == -INFINITY ? 0.f : sa * __expf(ma - mm))
           + (mb == -INFINITY ? 0.f : sb * __expf(mb - mm));
      smax[t] = mm; ssum[t] = ss;
    }
    __syncthreads();
  }
  if (t == 0) {
    red[0] = smax[0];
    red[1] = ssum[0];
    *counter = 0;   // self-reset for next layer / replay
  }
}

// sl -> w = exp(sl - M), in place, x4 vectorized
__global__ void k_exp2(f32x4* __restrict__ slw, const float* __restrict__ red) {
  int i = blockIdx.x * 256 + threadIdx.x;
  int nvec = (N_EDGES + 3) / 4;
  if (i >= nvec) return;
  float M = red[0];
  f32x4 v = slw[i];
  v[0] = __expf(v[0] - M);
  v[1] = __expf(v[1] - M);
  v[2] = __expf(v[2] - M);
  v[3] = __expf(v[3] - M);
  slw[i] = v;
}

// ---------------- fused CSR aggregate: 16-edge x 16-lane layout + relu + LN + residual ----
// lane = g*16 + q : edge-subgroup g in [0,4), quarter-row q in [0,16) -> channels q*4..q*4+3
__global__ void k_agg_update(const int* __restrict__ rowptr,
                             const unsigned* __restrict__ packed,
                             const float* __restrict__ w,
                             const float* __restrict__ red,  // [1]=S
                             const float* __restrict__ hl,
                             const unsigned char* __restrict__ hl8,
                             const float* __restrict__ gam,
                             const float* __restrict__ bet,
                             float* __restrict__ h) {
  int wave = threadIdx.x >> 6, lane = threadIdx.x & 63;
  int n = blockIdx.x * 4 + wave;
  if (n >= N_NODES) return;
  int g = lane >> 4, q = lane & 15;
  int beg = rowptr[n];
  int end = rowptr[n + 1];

  float a0 = 0.f, a1 = 0.f, a2 = 0.f, a3 = 0.f;
  for (int k = beg; k < end; k += 16) {
    int ke0 = k + g, ke1 = k + 4 + g, ke2 = k + 8 + g, ke3 = k + 12 + g;
    bool v0 = ke0 < end, v1 = ke1 < end, v2 = ke2 < end, v3 = ke3 < end;
    unsigned u0 = packed[v0 ? ke0 : beg];
    unsigned u1 = packed[v1 ? ke1 : beg];
    unsigned u2 = packed[v2 ? ke2 : beg];
    unsigned u3 = packed[v3 ? ke3 : beg];
    float w0 = v0 ? w[ke0] : 0.f;
    float w1 = v1 ? w[ke1] : 0.f;
    float w2 = v2 ? w[ke2] : 0.f;
    float w3 = v3 ? w[ke3] : 0.f;
    unsigned d0 = *(const unsigned*)(hl8 + (size_t)(u0 >> 15) * HID + q * 4);
    unsigned d1 = *(const unsigned*)(hl8 + (size_t)(u1 >> 15) * HID + q * 4);
    unsigned d2 = *(const unsigned*)(hl8 + (size_t)(u2 >> 15) * HID + q * 4);
    unsigned d3 = *(const unsigned*)(hl8 + (size_t)(u3 >> 15) * HID + q * 4);
#ifdef HAVE_PK_FP8
    f32x2 l0 = __builtin_amdgcn_cvt_pk_f32_fp8((int)d0, 0);
    f32x2 h0 = __builtin_amdgcn_cvt_pk_f32_fp8((int)d0, 1);
    f32x2 l1 = __builtin_amdgcn_cvt_pk_f32_fp8((int)d1, 0);
    f32x2 h1 = __builtin_amdgcn_cvt_pk_f32_fp8((int)d1, 1);
    f32x2 l2 = __builtin_amdgcn_cvt_pk_f32_fp8((int)d2, 0);
    f32x2 h2 = __builtin_amdgcn_cvt_pk_f32_fp8((int)d2, 1);
    f32x2 l3 = __builtin_amdgcn_cvt_pk_f32_fp8((int)d3, 0);
    f32x2 h3 = __builtin_amdgcn_cvt_pk_f32_fp8((int)d3, 1);
    a0 += w0 * l0[0] + w1 * l1[0] + w2 * l2[0] + w3 * l3[0];
    a1 += w0 * l0[1] + w1 * l1[1] + w2 * l2[1] + w3 * l3[1];
    a2 += w0 * h0[0] + w1 * h1[0] + w2 * h2[0] + w3 * h3[0];
    a3 += w0 * h0[1] + w1 * h1[1] + w2 * h2[1] + w3 * h3[1];
#else
    a0 += w0 * e42f(d0 & 0xffu) + w1 * e42f(d1 & 0xffu)
        + w2 * e42f(d2 & 0xffu) + w3 * e42f(d3 & 0xffu);
    a1 += w0 * e42f((d0 >> 8) & 0xffu) + w1 * e42f((d1 >> 8) & 0xffu)
        + w2 * e42f((d2 >> 8) & 0xffu) + w3 * e42f((d3 >> 8) & 0xffu);
    a2 += w0 * e42f((d0 >> 16) & 0xffu) + w1 * e42f((d1 >> 16) & 0xffu)
        + w2 * e42f((d2 >> 16) & 0xffu) + w3 * e42f((d3 >> 16) & 0xffu);
    a3 += w0 * e42f(d0 >> 24) + w1 * e42f(d1 >> 24)
        + w2 * e42f(d2 >> 24) + w3 * e42f(d3 >> 24);
#endif
  }
  // fold edge-subgroups (bits 4,5 of lane)
  a0 += __shfl_xor(a0, 16, 64); a0 += __shfl_xor(a0, 32, 64);
  a1 += __shfl_xor(a1, 16, 64); a1 += __shfl_xor(a1, 32, 64);
  a2 += __shfl_xor(a2, 16, 64); a2 += __shfl_xor(a2, 32, 64);
  a3 += __shfl_xor(a3, 16, 64); a3 += __shfl_xor(a3, 32, 64);

  float inv = 1.0f / red[1];
  const float* hlrow = hl + (size_t)n * HID + q * 4;
  float v0 = fmaxf(hlrow[0] + a0 * inv, 0.f);
  float v1 = fmaxf(hlrow[1] + a1 * inv, 0.f);
  float v2 = fmaxf(hlrow[2] + a2 * inv, 0.f);
  float v3 = fmaxf(hlrow[3] + a3 * inv, 0.f);

  float ms = v0 + v1 + v2 + v3;
  ms += __shfl_xor(ms, 1, 64); ms += __shfl_xor(ms, 2, 64);
  ms += __shfl_xor(ms, 4, 64); ms += __shfl_xor(ms, 8, 64);
  float m = ms * (1.0f / HID);
  float d0 = v0 - m, d1 = v1 - m, d2 = v2 - m, d3 = v3 - m;
  float vs = d0 * d0 + d1 * d1 + d2 * d2 + d3 * d3;
  vs += __shfl_xor(vs, 1, 64); vs += __shfl_xor(vs, 2, 64);
  vs += __shfl_xor(vs, 4, 64); vs += __shfl_xor(vs, 8, 64);
  float rs = rsqrtf(vs * (1.0f / HID) + LN_EPS);

  if (g == 0) {
    float* hrow = h + (size_t)n * HID + q * 4;
    f32x4 hv = *(const f32x4*)hrow;
    f32x4 gv = *(const f32x4*)(gam + q * 4);
    f32x4 bv = *(const f32x4*)(bet + q * 4);
    f32x4 o;
    o[0] = hv[0] + d0 * rs * gv[0] + bv[0];
    o[1] = hv[1] + d1 * rs * gv[1] + bv[1];
    o[2] = hv[2] + d2 * rs * gv[2] + bv[2];
    o[3] = hv[3] + d3 * rs * gv[3] + bv[3];
    *(f32x4*)hrow = o;
  }
}

// ---------------- output head via MFMA ----------------
__global__ void k_out_mfma(const float* __restrict__ h,
                           const float* __restrict__ W1,  // [64][32]
                           const float* __restrict__ b1,  // [32]
                           const float* __restrict__ W2,  // [32]
                           const float* __restrict__ b2,  // [1]
                           float* __restrict__ out) {
  __shared__ unsigned short W1t[32 * 72];  // W1t[m][k] bf16
  __shared__ float sW2[32];
  for (int idx = threadIdx.x; idx < HID * 32; idx += 256) {
    int k = idx >> 5, m = idx & 31;
    W1t[m * 72 + k] = f2bf(W1[idx]);
  }
  if (threadIdx.x < 32) sW2[threadIdx.x] = W2[threadIdx.x];
  __syncthreads();

  int wave = threadIdx.x >> 6, lane = threadIdx.x & 63;
  int g = lane >> 4, r = lane & 15;
  int nb = blockIdx.x * 64 + wave * 16;
  int row = nb + r;
  bool rowok = row < N_NODES;

  f32x4 f0 = {0,0,0,0}, f1 = {0,0,0,0}, f2v = {0,0,0,0}, f3 = {0,0,0,0};
  if (rowok) {
    const float* hrow = h + (size_t)row * HID;
    f0  = *(const f32x4*)(hrow + g * 8);
    f1  = *(const f32x4*)(hrow + g * 8 + 4);
    f2v = *(const f32x4*)(hrow + 32 + g * 8);
    f3  = *(const f32x4*)(hrow + 32 + g * 8 + 4);
  }
  bf16x8 a0, a1f;
#pragma unroll
  for (int i = 0; i < 4; ++i) {
    a0[i]      = (short)f2bf(f0[i]);
    a0[i + 4]  = (short)f2bf(f1[i]);
    a1f[i]     = (short)f2bf(f2v[i]);
    a1f[i + 4] = (short)f2bf(f3[i]);
  }

  f32x4 acc[2] = {{0,0,0,0},{0,0,0,0}};
#pragma unroll
  for (int mt = 0; mt < 2; ++mt) {
    bf16x8 b0 = *(const bf16x8*)&W1t[(mt * 16 + r) * 72 + g * 8];
    bf16x8 b1v = *(const bf16x8*)&W1t[(mt * 16 + r) * 72 + 32 + g * 8];
    acc[mt] = __builtin_amdgcn_mfma_f32_16x16x32_bf16(a0, b0, acc[mt], 0, 0, 0);
    acc[mt] = __builtin_amdgcn_mfma_f32_16x16x32_bf16(a1f, b1v, acc[mt], 0, 0, 0);
  }

  float part[4];
#pragma unroll
  for (int reg = 0; reg < 4; ++reg) {
    float p = 0.f;
#pragma unroll
    for (int mt = 0; mt < 2; ++mt) {
      float z = acc[mt][reg] + b1[mt * 16 + r];
      p += fmaxf(z, 0.f) * sW2[mt * 16 + r];
    }
    p += __shfl_xor(p, 1, 64);
    p += __shfl_xor(p, 2, 64);
    p += __shfl_xor(p, 4, 64);
    p += __shfl_xor(p, 8, 64);
    part[reg] = p;
  }
  if (r == 0) {
    float bb = b2[0];
#pragma unroll
    for (int reg = 0; reg < 4; ++reg) {
      int n2 = nb + g * 4 + reg;
      if (n2 < N_NODES)
        out[n2] = 1.0f / (1.0f + expf(-(part[reg] + bb)));
    }
  }
}

extern "C" void kernel_launch(void* const* d_in, const int* in_sizes, int n_in,
                              void* d_out, int out_size, void* d_ws, size_t ws_size,
                              hipStream_t stream) {
  const float* x      = (const float*)d_in[0];
  const int*   ei     = (const int*)d_in[1];     // [2][E]
  const float* ew     = (const float*)d_in[2];
  const float* in_W   = (const float*)d_in[3];
  const float* in_b   = (const float*)d_in[4];
  const float* lin_W  = (const float*)d_in[5];   // [3][64][64]
  const float* lin_b  = (const float*)d_in[6];   // [3][64]
  const float* att_W  = (const float*)d_in[7];   // [3][128]
  const float* att_b  = (const float*)d_in[8];   // [3]
  const float* ln_g   = (const float*)d_in[9];   // [3][64]
  const float* ln_b   = (const float*)d_in[10];  // [3][64]
  const float* out1_W = (const float*)d_in[11];  // [64][32]
  const float* out1_b = (const float*)d_in[12];  // [32]
  const float* out2_W = (const float*)d_in[13];  // [32]
  const float* out2_b = (const float*)d_in[14];  // [1]
  float* out = (float*)d_out;

  float* ws = (float*)d_ws;
  float* h            = ws;                         // 6.4M f
  float* hl           = ws + 6400000;               // 6.4M f
  unsigned char* hl8  = (unsigned char*)(ws + 12800000);       // 6.4M bytes
  unsigned long long* tmp = (unsigned long long*)(ws + 14500000);  // 1.25M u64
  unsigned* packed    = (unsigned*)(ws + 17000000); // 1.25M u32
  float* slw          = ws + 18250000;              // 1.25M f; 16B-aligned
  int* rowptr         = (int*)(ws + 19500000);      // N_NODES+1
  int* counter        = (int*)(ws + 19601000);      // 1 int (ticket)
  unsigned* bcnt      = (unsigned*)(counter + 1);   // 256 (memset with counter)
  unsigned* boffs     = bcnt + 256;                 // 257
  float* alpha1       = ws + 19702000;
  float* alpha2       = ws + 19803000;
  float* pmax         = ws + 19904000;              // 1024
  float* psum         = ws + 19906000;              // 1024
  float* red          = ws + 19908000;              // [0]=M, [1]=S
  float* uvec         = ws + 19909000;              // [3][2][64]
  float* ucst         = ws + 19910000;              // [3][2]
  unsigned* gbcur     = (unsigned*)(ws + 19912000); // 256

  // ---- one-time CSR build (bucketed, no global per-node atomics) ----
  hipMemsetAsync(counter, 0, (1 + 256) * sizeof(int), stream);  // ticket + bcnt
  k_bhist<<<P1_BLOCKS, 256, 0, stream>>>(ei, bcnt);
  k_bscan<<<1, 256, 0, stream>>>(bcnt, boffs, gbcur, rowptr);
  k_fill_p1<<<P1_BLOCKS, 256, 0, stream>>>(ei, ew, gbcur, tmp);
  k_fill_p2<<<BUCKETS, 512, 0, stream>>>(boffs, tmp, rowptr, packed);

  k_prep<<<N_LAYERS, 64, 0, stream>>>(lin_W, lin_b, att_W, uvec, ucst);
  k_in_proj<<<NODE_BLOCKS, 256, 0, stream>>>(x, in_W, in_b, h);

  for (int i = 0; i < N_LAYERS; ++i) {
    k_lin_mfma<<<MFMA_BLOCKS2, 256, 0, stream>>>(h, lin_W + i * HID * HID, lin_b + i * HID,
                                                 uvec + i * 128, ucst + i * 2,
                                                 hl, hl8, alpha1, alpha2);
    k_edge<<<NEDGE_BLOCKS, 256, 0, stream>>>(rowptr, packed, alpha1, alpha2,
                                             att_b + i, slw, pmax, psum, counter, red);
    k_exp2<<<(((N_EDGES + 3) / 4) + 255) / 256, 256, 0, stream>>>((f32x4*)slw, red);
    k_agg_update<<<NODE_BLOCKS, 256, 0, stream>>>(rowptr, packed, slw, red,
                                                  hl, hl8, ln_g + i * HID, ln_b + i * HID, h);
  }

  k_out_mfma<<<OUT_BLOCKS, 256, 0, stream>>>(h, out1_W, out1_b, out2_W, out2_b, out);
}